// Round 7
// baseline (621.025 us; speedup 1.0000x reference)
//
#include <hip/hip_runtime.h>
#include <stdint.h>

typedef unsigned short u16;
typedef __bf16 bf16x8 __attribute__((ext_vector_type(8)));
typedef short s16x8 __attribute__((ext_vector_type(8)));
typedef short s16x4 __attribute__((ext_vector_type(4)));
typedef float f32x4 __attribute__((ext_vector_type(4)));

__device__ __forceinline__ u16 f2bf(float f) {
  uint32_t u = __builtin_bit_cast(uint32_t, f);
  u += 0x7fffu + ((u >> 16) & 1u);
  return (u16)(u >> 16);
}
__device__ __forceinline__ float bf2f(u16 h) {
  uint32_t u = ((uint32_t)h) << 16;
  return __builtin_bit_cast(float, u);
}

// async global->LDS, 16B per lane, wave-uniform LDS base + lane*16
__device__ __forceinline__ void gl16(const u16* g, u16* l) {
  __builtin_amdgcn_global_load_lds(
      (const __attribute__((address_space(1))) void*)g,
      (__attribute__((address_space(3))) void*)l, 16, 0, 0);
}

// s_barrier that is also a compiler memory fence
__device__ __forceinline__ void barf() {
  asm volatile("s_barrier" ::: "memory");
}

// ---- T2 LDS XOR-swizzle (verified r5: bank conflicts -> 0) ----
__device__ __forceinline__ int src_chunk(int l) {
  return (((l & 3) ^ ((l >> 3) & 3)) * 8);
}
__device__ __forceinline__ int rd_koff(int l) {
  return (((l >> 4) ^ (((l & 15) >> 1) & 3)) * 8);
}

// ---------------- input converts ----------------
__global__ void cvt_in2(const float* __restrict__ a, const float* __restrict__ b,
                        u16* __restrict__ da, u16* __restrict__ db, long n8each) {
  long stride = (long)gridDim.x * blockDim.x;
  long total = 2 * n8each;
  for (long i = (long)blockIdx.x * blockDim.x + threadIdx.x; i < total; i += stride) {
    const float* src = (i < n8each) ? a + i * 8 : b + (i - n8each) * 8;
    u16* dst = (i < n8each) ? da + i * 8 : db + (i - n8each) * 8;
    const f32x4* s = (const f32x4*)src;
    f32x4 v0 = s[0], v1 = s[1];
    s16x8 o;
#pragma unroll
    for (int j = 0; j < 4; ++j) o[j] = (short)f2bf(v0[j]);
#pragma unroll
    for (int j = 0; j < 4; ++j) o[4 + j] = (short)f2bf(v1[j]);
    *(s16x8*)dst = o;
  }
}

__global__ void cvt_flat8(const float* __restrict__ src, u16* __restrict__ dst,
                          long n8, float scale) {
  long stride = (long)gridDim.x * blockDim.x;
  for (long i = (long)blockIdx.x * blockDim.x + threadIdx.x; i < n8; i += stride) {
    const f32x4* s = (const f32x4*)(src + i * 8);
    f32x4 a = s[0], b = s[1];
    s16x8 o;
#pragma unroll
    for (int j = 0; j < 4; ++j) o[j] = (short)f2bf(a[j] * scale);
#pragma unroll
    for (int j = 0; j < 4; ++j) o[4 + j] = (short)f2bf(b[j] * scale);
    *(s16x8*)(dst + i * 8) = o;
  }
}

// ---------------- weight prep ----------------
__global__ void prep_w(const float* __restrict__ c_wg, const float* __restrict__ c_wp,
                       const float* __restrict__ p_wg, const float* __restrict__ p_wp,
                       const float* __restrict__ c_wt, const float* __restrict__ p_wt,
                       const float* __restrict__ c_ww, const float* __restrict__ p_ww,
                       u16* __restrict__ wcat, u16* __restrict__ wt_c,
                       u16* __restrict__ wt_p, u16* __restrict__ ww_c,
                       u16* __restrict__ ww_p) {
  const int C0 = 1280 * 768 / 4;
  const int C1 = C0 + 384 * 768 / 4;
  const int C2 = C1 + 256 * 768 / 4;
  const int C3 = C2 + 768 * 384 / 4;
  const int C4 = C3 + 768 * 256 / 4;
  int stride = gridDim.x * blockDim.x;
  for (int i = blockIdx.x * blockDim.x + threadIdx.x; i < C4; i += stride) {
    const float* src = nullptr;
    u16* dst;
    if (i < C0) {
      int e = i * 4;
      dst = wcat + e;
      int r = e / 768;
      if (r < 384) src = c_wg + e;
      else if (r < 768) src = c_wp + e - 384 * 768;
      else if (r < 960) src = p_wg + e - 768 * 768;
      else if (r < 1024) src = nullptr;
      else if (r < 1216) src = p_wp + e - 1024 * 768;
      else src = nullptr;
    } else if (i < C1) {
      int e = (i - C0) * 4; dst = wt_c + e; src = c_wt + e;
    } else if (i < C2) {
      int e = (i - C1) * 4; dst = wt_p + e;
      src = (e / 768 < 192) ? p_wt + e : nullptr;
    } else if (i < C3) {
      int e = (i - C2) * 4; dst = ww_c + e; src = c_ww + e;
    } else {
      int e = (i - C3) * 4; dst = ww_p + e;
      int r = e >> 8, c = e & 255;
      src = (c < 192) ? p_ww + r * 192 + c : nullptr;
    }
    s16x4 o;
    if (src) {
      f32x4 v = *(const f32x4*)src;
#pragma unroll
      for (int j = 0; j < 4; ++j) o[j] = (short)f2bf(v[j]);
    } else {
      o = s16x4{0, 0, 0, 0};
    }
    *(s16x4*)dst = o;
  }
}

// biasb[1920] + zero sums[0..24575] (2 x 8 replicas x 1536)
__global__ void prep_b(const float* __restrict__ c_bg, const float* __restrict__ c_bp,
                       const float* __restrict__ p_bg, const float* __restrict__ p_bp,
                       const float* __restrict__ c_bt, const float* __restrict__ p_bt,
                       float* __restrict__ biasb, float* __restrict__ sums) {
  int i = blockIdx.x * blockDim.x + threadIdx.x;
  if (i < 1920) {
    float v = 0.f;
    if (i < 384) v = c_bg[i];
    else if (i < 768) v = c_bp[i - 384];
    else if (i < 960) v = p_bg[i - 768];
    else if (i < 1024) v = 0.f;
    else if (i < 1216) v = p_bp[i - 1024];
    else if (i < 1280) v = 0.f;
    else if (i < 1664) v = c_bt[i - 1280];
    else if (i < 1856) v = p_bt[i - 1664];
    biasb[i] = v;
  } else if (i < 1920 + 24576) {
    sums[i - 1920] = 0.f;
  }
}

// ======== big NT GEMM: 256x256 tile, BK=32, 8 waves, 4-slot LDS ring ========
// r5-exact 2-phase schedule; epilogue via swapped MFMA operands:
// acc[mi][ni] reg j = C[16mi + (l&15)][16ni + (l>>4)*4 + j]
template <int BIAS, int SUMS>
__global__ __launch_bounds__(512) void gemm_nt_big(
    const u16* __restrict__ A, const u16* __restrict__ B, void* __restrict__ Cv,
    const float* __restrict__ bias, float* __restrict__ sums,
    int ntiles, long lda, long ldb, long ldc, int K,
    long aBatch, long bBatch, long cBatch) {
  __shared__ u16 As[4][256 * 32];
  __shared__ u16 Bs[4][256 * 32];

  const int bm = blockIdx.x / ntiles;
  const int bn = blockIdx.x % ntiles;
  const int bb = blockIdx.y;
  const int nt = K >> 5;

  const u16* Ab = A + (long)bb * aBatch + (long)bm * 256 * lda;
  const u16* Bb = B + (long)bb * bBatch + (long)bn * 256 * ldb;

  const int t = threadIdx.x;
  const int w = t >> 6;
  const int l = t & 63;
  const int wr = w >> 2;
  const int wc = w & 3;

  const int srow = w * 16 + (l >> 2);
  const int cg = src_chunk(l);
  const long aoff0 = (long)srow * lda + cg;
  const long aoff1 = (long)(128 + srow) * lda + cg;
  const long boff0 = (long)srow * ldb + cg;
  const long boff1 = (long)(128 + srow) * ldb + cg;

#define STAGE_A(T, BUF)                                   \
  gl16(Ab + aoff0 + (long)(T) * 32, &As[BUF][w * 512]);   \
  gl16(Ab + aoff1 + (long)(T) * 32, &As[BUF][(8 + w) * 512]);
#define STAGE_B(T, BUF)                                   \
  gl16(Bb + boff0 + (long)(T) * 32, &Bs[BUF][w * 512]);   \
  gl16(Bb + boff1 + (long)(T) * 32, &Bs[BUF][(8 + w) * 512]);

  f32x4 acc[8][4] = {};

  STAGE_A(0, 0); STAGE_B(0, 0);
  if (nt > 1) { STAGE_A(1, 1); STAGE_B(1, 1); }
  if (nt > 2) { STAGE_A(2, 2); STAGE_B(2, 2); }
  if (nt > 2)      asm volatile("s_waitcnt vmcnt(8)" ::: "memory");
  else if (nt > 1) asm volatile("s_waitcnt vmcnt(4)" ::: "memory");
  else             asm volatile("s_waitcnt vmcnt(0)" ::: "memory");
  barf();

  const int koff = rd_koff(l);
  const int ar = wr * 128 + (l & 15);
  const int br = wc * 64 + (l & 15);

  for (int tt = 0; tt < nt; ++tt) {
    const int cur = tt & 3;
    const int pf = (tt + 3) & 3;
    const bool do_pf = (tt + 3) < nt;

    // ---- phase 0: B frags + A frags(m0..3); stage A of tile tt+3 ----
    bf16x8 bfr[4], af[4];
#pragma unroll
    for (int ni = 0; ni < 4; ++ni)
      bfr[ni] = __builtin_bit_cast(
          bf16x8, *(const s16x8*)(&Bs[cur][(br + ni * 16) * 32 + koff]));
#pragma unroll
    for (int mi = 0; mi < 4; ++mi)
      af[mi] = __builtin_bit_cast(
          bf16x8, *(const s16x8*)(&As[cur][(ar + mi * 16) * 32 + koff]));
    if (do_pf) { STAGE_A(tt + 3, pf); }
    barf();
    __builtin_amdgcn_s_setprio(1);
#pragma unroll
    for (int mi = 0; mi < 4; ++mi)
#pragma unroll
      for (int ni = 0; ni < 4; ++ni)
        acc[mi][ni] = __builtin_amdgcn_mfma_f32_16x16x32_bf16(
            bfr[ni], af[mi], acc[mi][ni], 0, 0, 0);
    __builtin_amdgcn_s_setprio(0);
    barf();

    // ---- phase 1: A frags(m4..7); stage B of tile tt+3 ----
    bf16x8 ag[4];
#pragma unroll
    for (int mi = 0; mi < 4; ++mi)
      ag[mi] = __builtin_bit_cast(
          bf16x8, *(const s16x8*)(&As[cur][(ar + 64 + mi * 16) * 32 + koff]));
    if (do_pf) { STAGE_B(tt + 3, pf); }
    barf();
    __builtin_amdgcn_s_setprio(1);
#pragma unroll
    for (int mi = 0; mi < 4; ++mi)
#pragma unroll
      for (int ni = 0; ni < 4; ++ni)
        acc[4 + mi][ni] = __builtin_amdgcn_mfma_f32_16x16x32_bf16(
            bfr[ni], ag[mi], acc[4 + mi][ni], 0, 0, 0);
    __builtin_amdgcn_s_setprio(0);
    if (tt + 4 <= nt)      asm volatile("s_waitcnt vmcnt(8)" ::: "memory");
    else if (tt + 3 == nt) asm volatile("s_waitcnt vmcnt(4)" ::: "memory");
    else if (tt + 2 == nt) asm volatile("s_waitcnt vmcnt(0)" ::: "memory");
    barf();
  }
#undef STAGE_A
#undef STAGE_B
  __builtin_amdgcn_sched_barrier(0);

  const long crow0 = (long)bm * 256 + wr * 128;
  const long ccol0 = (long)bn * 256 + wc * 64;
  u16* C = (u16*)Cv + (long)bb * cBatch;
#pragma unroll
  for (int mi = 0; mi < 8; ++mi) {
    long row = crow0 + mi * 16 + (l & 15);
    float rb = (BIAS == 1) ? bias[row] : 0.f;
    u16* Cr = C + row * ldc + ccol0 + (l >> 4) * 4;
#pragma unroll
    for (int ni = 0; ni < 4; ++ni) {
      s16x4 v;
#pragma unroll
      for (int j = 0; j < 4; ++j) v[j] = (short)f2bf(acc[mi][ni][j] + rb);
      *(s16x4*)(Cr + ni * 16) = v;  // 8B coalesced store
    }
  }

  if (SUMS) {
    float* srep = sums + (blockIdx.x & 7) * 1536;
#pragma unroll
    for (int ni = 0; ni < 4; ++ni) {
      f32x4 s = {}, q = {};
#pragma unroll
      for (int mi = 0; mi < 8; ++mi)
#pragma unroll
        for (int j = 0; j < 4; ++j) {
          float v = acc[mi][ni][j];
          s[j] += v;
          q[j] += v * v;
        }
      // reduce over the 16 row-lanes (bits 0-3 of l)
#pragma unroll
      for (int m = 1; m < 16; m <<= 1) {
#pragma unroll
        for (int j = 0; j < 4; ++j) {
          s[j] += __shfl_xor(s[j], m);
          q[j] += __shfl_xor(q[j], m);
        }
      }
      if ((l & 15) == 0) {
        long cb = ccol0 + ni * 16 + (l >> 4) * 4;
#pragma unroll
        for (int j = 0; j < 4; ++j) {
          atomicAdd(&srep[cb + j], s[j]);
          atomicAdd(&srep[768 + cb + j], q[j]);
        }
      }
    }
  }
}

// -------- generic NT GEMM (128x128, 4 waves), r5-exact 2-slot schedule --------
template <int BIAS, int OUT_ATOMIC, int SUMS>
__global__ __launch_bounds__(256) void gemm_nt(
    const u16* __restrict__ A, const u16* __restrict__ B, void* __restrict__ Cv,
    const float* __restrict__ bias, float* __restrict__ sums,
    int ntiles, long lda, long ldb, long ldc, int K,
    long aBatch, long bBatch, long cBatch) {
  __shared__ u16 As[2][128 * 32];
  __shared__ u16 Bs[2][128 * 32];

  const int bm = blockIdx.x / ntiles;
  const int bn = blockIdx.x % ntiles;
  const int bb = blockIdx.y;
  const int kChunk = K / gridDim.z;
  const long k0base = (long)blockIdx.z * kChunk;
  const int nt = kChunk >> 5;

  const u16* Ab = A + (long)bb * aBatch + (long)bm * 128 * lda + k0base;
  const u16* Bb = B + (long)bb * bBatch + (long)bn * 128 * ldb + k0base;

  const int t = threadIdx.x;
  const int w = t >> 6;
  const int l = t & 63;
  const int wr = w >> 1, wc = w & 1;

  const int cg = src_chunk(l);
  const long aoff = (long)(32 * w + (l >> 2)) * lda + cg;
  const long boff = (long)(32 * w + (l >> 2)) * ldb + cg;

  f32x4 acc[4][4] = {};

  gl16(Ab + aoff, &As[0][(32 * w) * 32]);
  gl16(Ab + aoff + 16 * lda, &As[0][(32 * w + 16) * 32]);
  gl16(Bb + boff, &Bs[0][(32 * w) * 32]);
  gl16(Bb + boff + 16 * ldb, &Bs[0][(32 * w + 16) * 32]);
  if (nt > 1) {
    gl16(Ab + aoff + 32, &As[1][(32 * w) * 32]);
    gl16(Ab + aoff + 16 * lda + 32, &As[1][(32 * w + 16) * 32]);
    gl16(Bb + boff + 32, &Bs[1][(32 * w) * 32]);
    gl16(Bb + boff + 16 * ldb + 32, &Bs[1][(32 * w + 16) * 32]);
  }

  const int koff = rd_koff(l);

  for (int tt = 0; tt < nt; ++tt) {
    const int cur = tt & 1;
    if (tt + 1 < nt)
      asm volatile("s_waitcnt vmcnt(4)" ::: "memory");
    else
      asm volatile("s_waitcnt vmcnt(0)" ::: "memory");
    __builtin_amdgcn_s_barrier();

    bf16x8 af[4], bfr[4];
#pragma unroll
    for (int mi = 0; mi < 4; ++mi)
      af[mi] = __builtin_bit_cast(
          bf16x8, *(const s16x8*)(&As[cur][(wr * 64 + mi * 16 + (l & 15)) * 32 + koff]));
#pragma unroll
    for (int ni = 0; ni < 4; ++ni)
      bfr[ni] = __builtin_bit_cast(
          bf16x8, *(const s16x8*)(&Bs[cur][(wc * 64 + ni * 16 + (l & 15)) * 32 + koff]));
#pragma unroll
    for (int mi = 0; mi < 4; ++mi)
#pragma unroll
      for (int ni = 0; ni < 4; ++ni)
        acc[mi][ni] = __builtin_amdgcn_mfma_f32_16x16x32_bf16(
            bfr[ni], af[mi], acc[mi][ni], 0, 0, 0);

    __builtin_amdgcn_s_barrier();
    if (tt + 2 < nt) {
      const long ko = (long)(tt + 2) * 32;
      gl16(Ab + aoff + ko, &As[cur][(32 * w) * 32]);
      gl16(Ab + aoff + 16 * lda + ko, &As[cur][(32 * w + 16) * 32]);
      gl16(Bb + boff + ko, &Bs[cur][(32 * w) * 32]);
      gl16(Bb + boff + 16 * ldb + ko, &Bs[cur][(32 * w + 16) * 32]);
    }
  }
  __builtin_amdgcn_sched_barrier(0);

  const long crow0 = (long)bm * 128 + wr * 64;
  const long ccol0 = (long)bn * 128 + wc * 64;

  if (OUT_ATOMIC) {
    float* C = (float*)Cv + (long)bb * cBatch;
#pragma unroll
    for (int mi = 0; mi < 4; ++mi) {
      long row = crow0 + mi * 16 + (l & 15);
#pragma unroll
      for (int ni = 0; ni < 4; ++ni) {
        long cb = ccol0 + ni * 16 + (l >> 4) * 4;
#pragma unroll
        for (int j = 0; j < 4; ++j)
          atomicAdd(&C[row * ldc + cb + j], acc[mi][ni][j]);
      }
    }
  } else {
    u16* C = (u16*)Cv + (long)bb * cBatch;
#pragma unroll
    for (int mi = 0; mi < 4; ++mi) {
      long row = crow0 + mi * 16 + (l & 15);
      float rb = (BIAS == 1) ? bias[row] : 0.f;
      u16* Cr = C + row * ldc + ccol0 + (l >> 4) * 4;
#pragma unroll
      for (int ni = 0; ni < 4; ++ni) {
        f32x4 cbv = {};
        if (BIAS == 2)
          cbv = *(const f32x4*)(bias + ccol0 + ni * 16 + (l >> 4) * 4);
        s16x4 v;
#pragma unroll
        for (int j = 0; j < 4; ++j)
          v[j] = (short)f2bf(acc[mi][ni][j] + rb + cbv[j]);
        *(s16x4*)(Cr + ni * 16) = v;
      }
    }
  }

  if (SUMS) {
    float* srep = sums + (blockIdx.x & 7) * 1536;
#pragma unroll
    for (int ni = 0; ni < 4; ++ni) {
      f32x4 s = {}, q = {};
#pragma unroll
      for (int mi = 0; mi < 4; ++mi)
#pragma unroll
        for (int j = 0; j < 4; ++j) {
          float v = acc[mi][ni][j];
          s[j] += v;
          q[j] += v * v;
        }
#pragma unroll
      for (int m = 1; m < 16; m <<= 1) {
#pragma unroll
        for (int j = 0; j < 4; ++j) {
          s[j] += __shfl_xor(s[j], m);
          q[j] += __shfl_xor(q[j], m);
        }
      }
      if ((l & 15) == 0) {
        long cb = ccol0 + ni * 16 + (l >> 4) * 4;
#pragma unroll
        for (int j = 0; j < 4; ++j) {
          atomicAdd(&srep[cb + j], s[j]);
          atomicAdd(&srep[768 + cb + j], q[j]);
        }
      }
    }
  }
}

// ---------------- BN ----------------
__global__ void bn_stats(const float* __restrict__ sums, const float* __restrict__ gamma,
                         const float* __restrict__ beta, float* __restrict__ stats,
                         float invN) {
  int c = threadIdx.x;
  float s = 0.f, q = 0.f;
#pragma unroll
  for (int r = 0; r < 8; ++r) {
    s += sums[r * 1536 + c];
    q += sums[r * 1536 + 768 + c];
  }
  float mu = s * invN;
  float var = q * invN - mu * mu;
  float sc = gamma[c] * rsqrtf(var + 1e-5f);
  stats[c] = sc;
  stats[768 + c] = beta[c] - mu * sc;
}

template <int OUT_F32>
__global__ void bn_apply(const u16* __restrict__ pre, const u16* __restrict__ resid,
                         const float* __restrict__ stats, void* __restrict__ out,
                         long n8) {
  long stride = (long)gridDim.x * blockDim.x;
  for (long i = (long)blockIdx.x * blockDim.x + threadIdx.x; i < n8; i += stride) {
    long base = i * 8;
    int c = (int)(base % 768);
    f32x4 sc0 = *(const f32x4*)(stats + c);
    f32x4 sc1 = *(const f32x4*)(stats + c + 4);
    f32x4 sh0 = *(const f32x4*)(stats + 768 + c);
    f32x4 sh1 = *(const f32x4*)(stats + 768 + c + 4);
    s16x8 p = *(const s16x8*)(pre + base);
    s16x8 rv = *(const s16x8*)(resid + base);
    float o[8];
#pragma unroll
    for (int j = 0; j < 4; ++j)
      o[j] = bf2f((u16)p[j]) * sc0[j] + sh0[j] + bf2f((u16)rv[j]);
#pragma unroll
    for (int j = 0; j < 4; ++j)
      o[4 + j] = bf2f((u16)p[4 + j]) * sc1[j] + sh1[j] + bf2f((u16)rv[4 + j]);
    if (OUT_F32) {
      f32x4 o0, o1;
#pragma unroll
      for (int j = 0; j < 4; ++j) { o0[j] = o[j]; o1[j] = o[4 + j]; }
      f32x4* op = (f32x4*)((float*)out + base);
      op[0] = o0;
      op[1] = o1;
    } else {
      s16x8 ov;
#pragma unroll
      for (int j = 0; j < 8; ++j) ov[j] = (short)f2bf(o[j]);
      *(s16x8*)((u16*)out + base) = ov;
    }
  }
}

extern "C" void kernel_launch(void* const* d_in, const int* in_sizes, int n_in,
                              void* d_out, int out_size, void* d_ws, size_t ws_size,
                              hipStream_t stream) {
  const float* x = (const float*)d_in[0];
  const float* x0 = (const float*)d_in[1];
  const float* c_wg = (const float*)d_in[2];
  const float* c_bg = (const float*)d_in[3];
  const float* c_wt = (const float*)d_in[4];
  const float* c_bt = (const float*)d_in[5];
  const float* c_wp = (const float*)d_in[6];
  const float* c_bp = (const float*)d_in[7];
  const float* c_ww = (const float*)d_in[8];
  const float* c_gamma = (const float*)d_in[10];
  const float* c_beta = (const float*)d_in[11];
  const float* p_wg = (const float*)d_in[12];
  const float* p_bg = (const float*)d_in[13];
  const float* p_wt = (const float*)d_in[14];
  const float* p_bt = (const float*)d_in[15];
  const float* p_wp = (const float*)d_in[16];
  const float* p_bp = (const float*)d_in[17];
  const float* p_ww = (const float*)d_in[18];
  const float* p_gamma = (const float*)d_in[20];
  const float* p_beta = (const float*)d_in[21];

  char* ws = (char*)d_ws;
  const long NT = 32768;
  u16* xbf = (u16*)(ws + 0);
  u16* x0bf = (u16*)(ws + 50331648);
  u16* th = (u16*)(ws + 50331648);
  float* kvf_c = (float*)(ws + 75497472);
  float* kvf_p = (float*)(ws + 80216064);
  u16* kvb = (u16*)(ws + 82313216);
  u16* kvwT = (u16*)(ws + 84672512);
  u16* gphT = (u16*)(ws + 100663296);
  u16* wcat = (u16*)(ws + 184549376);
  u16* wt_c = (u16*)(ws + 186515456);
  u16* wt_p = (u16*)(ws + 187105280);
  u16* ww_c = (u16*)(ws + 187498496);
  u16* ww_p = (u16*)(ws + 188088320);
  float* biasb = (float*)(ws + 188481536);
  float* sums = (float*)(ws + 188489216);   // 2 x 8 x 1536 floats
  float* stats = (float*)(ws + 188587520);  // 1536 floats
  u16* zbf = xbf;
  u16* pre = gphT;

  // ---- prep ----
  cvt_in2<<<4096, 256, 0, stream>>>(x, x0, xbf, x0bf, NT * 768 / 8);
  prep_w<<<480, 256, 0, stream>>>(c_wg, c_wp, p_wg, p_wp, c_wt, p_wt, c_ww, p_ww,
                                  wcat, wt_c, wt_p, ww_c, ww_p);
  prep_b<<<104, 256, 0, stream>>>(c_bg, c_bp, p_bg, p_bp, c_bt, p_bt, biasb, sums);

  // ---- fused gphT[1280][32768] = Wcat @ x0^T (+row bias) ----
  gemm_nt_big<1, 0><<<dim3(5 * 128, 1, 1), 512, 0, stream>>>(
      wcat, x0bf, gphT, biasb, nullptr, 128, 768, 768, 32768, 768, 0, 0, 0);
  hipMemsetAsync(kvf_c, 0, 4718592 + 2097152, stream);

  // ================= CNL (D=384) =================
  gemm_nt<2, 0, 0><<<dim3(256 * 3, 1, 1), 256, 0, stream>>>(
      xbf, wt_c, th, biasb + 1280, nullptr, 3, 768, 768, 384, 768, 0, 0, 0);
  gemm_nt<0, 1, 0><<<dim3(9, 8, 8), 256, 0, stream>>>(
      gphT + (long)384 * 32768, gphT, kvf_c, nullptr, nullptr, 3, 32768, 32768,
      384, 4096, 4096, 4096, (long)384 * 384);
  cvt_flat8<<<576, 256, 0, stream>>>(kvf_c, kvb, (long)8 * 384 * 384 / 8, 1.f / 4096.f);
  gemm_nt<0, 0, 0><<<dim3(18, 8, 1), 256, 0, stream>>>(
      ww_c, kvb, kvwT, nullptr, nullptr, 3, 384, 384, 384, 384, 0,
      (long)384 * 384, (long)768 * 384);
  gemm_nt_big<0, 1><<<dim3(48, 8, 1), 512, 0, stream>>>(
      th, kvwT, pre, nullptr, sums, 3, 384, 384, 768, 384, (long)4096 * 384,
      (long)768 * 384, (long)4096 * 768);
  bn_stats<<<1, 768, 0, stream>>>(sums, c_gamma, c_beta, stats, 1.f / 32768.f);
  bn_apply<0><<<2048, 256, 0, stream>>>(pre, xbf, stats, zbf, NT * 768 / 8);

  // ================= PNL (D=192, padded to 256) =================
  gemm_nt<2, 0, 0><<<dim3(256 * 2, 1, 1), 256, 0, stream>>>(
      zbf, wt_p, th, biasb + 1664, nullptr, 2, 768, 768, 256, 768, 0, 0, 0);
  gemm_nt<0, 1, 0><<<dim3(4, 8, 8), 256, 0, stream>>>(
      gphT + (long)1024 * 32768, gphT + (long)768 * 32768, kvf_p, nullptr, nullptr,
      2, 32768, 32768, 256, 4096, 4096, 4096, (long)256 * 256);
  cvt_flat8<<<256, 256, 0, stream>>>(kvf_p, kvb, (long)8 * 256 * 256 / 8, 1.f / 4096.f);
  gemm_nt<0, 0, 0><<<dim3(12, 8, 1), 256, 0, stream>>>(
      ww_p, kvb, kvwT, nullptr, nullptr, 2, 256, 256, 256, 256, 0,
      (long)256 * 256, (long)768 * 256);
  gemm_nt_big<0, 1><<<dim3(48, 8, 1), 512, 0, stream>>>(
      th, kvwT, pre, nullptr, sums + 8 * 1536, 3, 256, 256, 768, 256,
      (long)4096 * 256, (long)768 * 256, (long)4096 * 768);
  bn_stats<<<1, 768, 0, stream>>>(sums + 8 * 1536, p_gamma, p_beta, stats, 1.f / 32768.f);
  bn_apply<1><<<2048, 256, 0, stream>>>(pre, zbf, stats, (float*)d_out, NT * 768 / 8);
}

// Round 8
// 486.173 us; speedup vs baseline: 1.2774x; 1.2774x over previous
//
#include <hip/hip_runtime.h>
#include <stdint.h>

typedef unsigned short u16;
typedef __bf16 bf16x8 __attribute__((ext_vector_type(8)));
typedef short s16x8 __attribute__((ext_vector_type(8)));
typedef short s16x4 __attribute__((ext_vector_type(4)));
typedef float f32x4 __attribute__((ext_vector_type(4)));

__device__ __forceinline__ u16 f2bf(float f) {
  uint32_t u = __builtin_bit_cast(uint32_t, f);
  u += 0x7fffu + ((u >> 16) & 1u);
  return (u16)(u >> 16);
}
__device__ __forceinline__ float bf2f(u16 h) {
  uint32_t u = ((uint32_t)h) << 16;
  return __builtin_bit_cast(float, u);
}

// async global->LDS, 16B per lane, wave-uniform LDS base + lane*16
__device__ __forceinline__ void gl16(const u16* g, u16* l) {
  __builtin_amdgcn_global_load_lds(
      (const __attribute__((address_space(1))) void*)g,
      (__attribute__((address_space(3))) void*)l, 16, 0, 0);
}

// s_barrier that is also a compiler memory fence
__device__ __forceinline__ void barf() {
  asm volatile("s_barrier" ::: "memory");
}

// ---- T2 LDS XOR-swizzle (verified r5: bank conflicts -> 0) ----
__device__ __forceinline__ int src_chunk(int l) {
  return (((l & 3) ^ ((l >> 3) & 3)) * 8);
}
__device__ __forceinline__ int rd_koff(int l) {
  return (((l >> 4) ^ (((l & 15) >> 1) & 3)) * 8);
}

// ---------------- input converts ----------------
__global__ void cvt_in2(const float* __restrict__ a, const float* __restrict__ b,
                        u16* __restrict__ da, u16* __restrict__ db, long n8each) {
  long stride = (long)gridDim.x * blockDim.x;
  long total = 2 * n8each;
  for (long i = (long)blockIdx.x * blockDim.x + threadIdx.x; i < total; i += stride) {
    const float* src = (i < n8each) ? a + i * 8 : b + (i - n8each) * 8;
    u16* dst = (i < n8each) ? da + i * 8 : db + (i - n8each) * 8;
    const f32x4* s = (const f32x4*)src;
    f32x4 v0 = s[0], v1 = s[1];
    s16x8 o;
#pragma unroll
    for (int j = 0; j < 4; ++j) o[j] = (short)f2bf(v0[j]);
#pragma unroll
    for (int j = 0; j < 4; ++j) o[4 + j] = (short)f2bf(v1[j]);
    *(s16x8*)dst = o;
  }
}

__global__ void cvt_flat8(const float* __restrict__ src, u16* __restrict__ dst,
                          long n8, float scale) {
  long stride = (long)gridDim.x * blockDim.x;
  for (long i = (long)blockIdx.x * blockDim.x + threadIdx.x; i < n8; i += stride) {
    const f32x4* s = (const f32x4*)(src + i * 8);
    f32x4 a = s[0], b = s[1];
    s16x8 o;
#pragma unroll
    for (int j = 0; j < 4; ++j) o[j] = (short)f2bf(a[j] * scale);
#pragma unroll
    for (int j = 0; j < 4; ++j) o[4 + j] = (short)f2bf(b[j] * scale);
    *(s16x8*)(dst + i * 8) = o;
  }
}

// ---------------- weight prep ----------------
__global__ void prep_w(const float* __restrict__ c_wg, const float* __restrict__ c_wp,
                       const float* __restrict__ p_wg, const float* __restrict__ p_wp,
                       const float* __restrict__ c_wt, const float* __restrict__ p_wt,
                       const float* __restrict__ c_ww, const float* __restrict__ p_ww,
                       u16* __restrict__ wcat, u16* __restrict__ wt_c,
                       u16* __restrict__ wt_p, u16* __restrict__ ww_c,
                       u16* __restrict__ ww_p) {
  const int C0 = 1280 * 768 / 4;
  const int C1 = C0 + 384 * 768 / 4;
  const int C2 = C1 + 256 * 768 / 4;
  const int C3 = C2 + 768 * 384 / 4;
  const int C4 = C3 + 768 * 256 / 4;
  int stride = gridDim.x * blockDim.x;
  for (int i = blockIdx.x * blockDim.x + threadIdx.x; i < C4; i += stride) {
    const float* src = nullptr;
    u16* dst;
    if (i < C0) {
      int e = i * 4;
      dst = wcat + e;
      int r = e / 768;
      if (r < 384) src = c_wg + e;
      else if (r < 768) src = c_wp + e - 384 * 768;
      else if (r < 960) src = p_wg + e - 768 * 768;
      else if (r < 1024) src = nullptr;
      else if (r < 1216) src = p_wp + e - 1024 * 768;
      else src = nullptr;
    } else if (i < C1) {
      int e = (i - C0) * 4; dst = wt_c + e; src = c_wt + e;
    } else if (i < C2) {
      int e = (i - C1) * 4; dst = wt_p + e;
      src = (e / 768 < 192) ? p_wt + e : nullptr;
    } else if (i < C3) {
      int e = (i - C2) * 4; dst = ww_c + e; src = c_ww + e;
    } else {
      int e = (i - C3) * 4; dst = ww_p + e;
      int r = e >> 8, c = e & 255;
      src = (c < 192) ? p_ww + r * 192 + c : nullptr;
    }
    s16x4 o;
    if (src) {
      f32x4 v = *(const f32x4*)src;
#pragma unroll
      for (int j = 0; j < 4; ++j) o[j] = (short)f2bf(v[j]);
    } else {
      o = s16x4{0, 0, 0, 0};
    }
    *(s16x4*)dst = o;
  }
}

// biasb[1920] + zero sums[0..24575] (2 x 8 replicas x 1536)
__global__ void prep_b(const float* __restrict__ c_bg, const float* __restrict__ c_bp,
                       const float* __restrict__ p_bg, const float* __restrict__ p_bp,
                       const float* __restrict__ c_bt, const float* __restrict__ p_bt,
                       float* __restrict__ biasb, float* __restrict__ sums) {
  int i = blockIdx.x * blockDim.x + threadIdx.x;
  if (i < 1920) {
    float v = 0.f;
    if (i < 384) v = c_bg[i];
    else if (i < 768) v = c_bp[i - 384];
    else if (i < 960) v = p_bg[i - 768];
    else if (i < 1024) v = 0.f;
    else if (i < 1216) v = p_bp[i - 1024];
    else if (i < 1280) v = 0.f;
    else if (i < 1664) v = c_bt[i - 1280];
    else if (i < 1856) v = p_bt[i - 1664];
    biasb[i] = v;
  } else if (i < 1920 + 24576) {
    sums[i - 1920] = 0.f;
  }
}

// ======== big NT GEMM: 256x256 tile, BK=32, 8 waves, 4-slot LDS ring ========
// r5 2-phase schedule; swapped-operand epilogue:
// acc[mi][ni] reg j = C[16mi + (l&15)][16ni + (l>>4)*4 + j]  -> s16x4 stores
template <int BIAS, int SUMS>
__global__ __launch_bounds__(512) void gemm_nt_big(
    const u16* __restrict__ A, const u16* __restrict__ B, void* __restrict__ Cv,
    const float* __restrict__ bias, float* __restrict__ sums,
    int ntiles, long lda, long ldb, long ldc, int K,
    long aBatch, long bBatch, long cBatch) {
  __shared__ u16 As[4][256 * 32];
  __shared__ u16 Bs[4][256 * 32];

  const int bm = blockIdx.x / ntiles;
  const int bn = blockIdx.x % ntiles;
  const int bb = blockIdx.y;
  const int nt = K >> 5;

  const u16* Ab = A + (long)bb * aBatch + (long)bm * 256 * lda;
  const u16* Bb = B + (long)bb * bBatch + (long)bn * 256 * ldb;

  const int t = threadIdx.x;
  const int w = t >> 6;
  const int l = t & 63;
  const int wr = w >> 2;
  const int wc = w & 3;

  const int srow = w * 16 + (l >> 2);
  const int cg = src_chunk(l);
  const long aoff0 = (long)srow * lda + cg;
  const long aoff1 = (long)(128 + srow) * lda + cg;
  const long boff0 = (long)srow * ldb + cg;
  const long boff1 = (long)(128 + srow) * ldb + cg;

#define STAGE_A(T, BUF)                                   \
  gl16(Ab + aoff0 + (long)(T) * 32, &As[BUF][w * 512]);   \
  gl16(Ab + aoff1 + (long)(T) * 32, &As[BUF][(8 + w) * 512]);
#define STAGE_B(T, BUF)                                   \
  gl16(Bb + boff0 + (long)(T) * 32, &Bs[BUF][w * 512]);   \
  gl16(Bb + boff1 + (long)(T) * 32, &Bs[BUF][(8 + w) * 512]);

  f32x4 acc[8][4] = {};

  STAGE_A(0, 0); STAGE_B(0, 0);
  if (nt > 1) { STAGE_A(1, 1); STAGE_B(1, 1); }
  if (nt > 2) { STAGE_A(2, 2); STAGE_B(2, 2); }
  if (nt > 2)      asm volatile("s_waitcnt vmcnt(8)" ::: "memory");
  else if (nt > 1) asm volatile("s_waitcnt vmcnt(4)" ::: "memory");
  else             asm volatile("s_waitcnt vmcnt(0)" ::: "memory");
  barf();

  const int koff = rd_koff(l);
  const int ar = wr * 128 + (l & 15);
  const int br = wc * 64 + (l & 15);

  for (int tt = 0; tt < nt; ++tt) {
    const int cur = tt & 3;
    const int pf = (tt + 3) & 3;
    const bool do_pf = (tt + 3) < nt;

    // ---- phase 0: B frags + A frags(m0..3); stage A of tile tt+3 ----
    bf16x8 bfr[4], af[4];
#pragma unroll
    for (int ni = 0; ni < 4; ++ni)
      bfr[ni] = __builtin_bit_cast(
          bf16x8, *(const s16x8*)(&Bs[cur][(br + ni * 16) * 32 + koff]));
#pragma unroll
    for (int mi = 0; mi < 4; ++mi)
      af[mi] = __builtin_bit_cast(
          bf16x8, *(const s16x8*)(&As[cur][(ar + mi * 16) * 32 + koff]));
    if (do_pf) { STAGE_A(tt + 3, pf); }
    barf();
    __builtin_amdgcn_s_setprio(1);
#pragma unroll
    for (int mi = 0; mi < 4; ++mi)
#pragma unroll
      for (int ni = 0; ni < 4; ++ni)
        acc[mi][ni] = __builtin_amdgcn_mfma_f32_16x16x32_bf16(
            bfr[ni], af[mi], acc[mi][ni], 0, 0, 0);
    __builtin_amdgcn_s_setprio(0);
    barf();

    // ---- phase 1: A frags(m4..7); stage B of tile tt+3 ----
    bf16x8 ag[4];
#pragma unroll
    for (int mi = 0; mi < 4; ++mi)
      ag[mi] = __builtin_bit_cast(
          bf16x8, *(const s16x8*)(&As[cur][(ar + 64 + mi * 16) * 32 + koff]));
    if (do_pf) { STAGE_B(tt + 3, pf); }
    barf();
    __builtin_amdgcn_s_setprio(1);
#pragma unroll
    for (int mi = 0; mi < 4; ++mi)
#pragma unroll
      for (int ni = 0; ni < 4; ++ni)
        acc[4 + mi][ni] = __builtin_amdgcn_mfma_f32_16x16x32_bf16(
            bfr[ni], ag[mi], acc[4 + mi][ni], 0, 0, 0);
    __builtin_amdgcn_s_setprio(0);
    if (tt + 4 <= nt)      asm volatile("s_waitcnt vmcnt(8)" ::: "memory");
    else if (tt + 3 == nt) asm volatile("s_waitcnt vmcnt(4)" ::: "memory");
    else if (tt + 2 == nt) asm volatile("s_waitcnt vmcnt(0)" ::: "memory");
    barf();
  }
#undef STAGE_A
#undef STAGE_B
  __builtin_amdgcn_sched_barrier(0);

  const long crow0 = (long)bm * 256 + wr * 128;
  const long ccol0 = (long)bn * 256 + wc * 64;
  u16* C = (u16*)Cv + (long)bb * cBatch;
#pragma unroll
  for (int mi = 0; mi < 8; ++mi) {
    long row = crow0 + mi * 16 + (l & 15);
    float rb = (BIAS == 1) ? bias[row] : 0.f;
    u16* Cr = C + row * ldc + ccol0 + (l >> 4) * 4;
#pragma unroll
    for (int ni = 0; ni < 4; ++ni) {
      s16x4 v;
#pragma unroll
      for (int j = 0; j < 4; ++j) v[j] = (short)f2bf(acc[mi][ni][j] + rb);
      *(s16x4*)(Cr + ni * 16) = v;  // 8B coalesced store
    }
  }

  if (SUMS) {
    float* srep = sums + (blockIdx.x & 7) * 1536;
#pragma unroll
    for (int ni = 0; ni < 4; ++ni) {
      f32x4 s = {}, q = {};
#pragma unroll
      for (int mi = 0; mi < 8; ++mi)
#pragma unroll
        for (int j = 0; j < 4; ++j) {
          float v = acc[mi][ni][j];
          s[j] += v;
          q[j] += v * v;
        }
#pragma unroll
      for (int m = 1; m < 16; m <<= 1) {
#pragma unroll
        for (int j = 0; j < 4; ++j) {
          s[j] += __shfl_xor(s[j], m);
          q[j] += __shfl_xor(q[j], m);
        }
      }
      if ((l & 15) == 0) {
        long cb = ccol0 + ni * 16 + (l >> 4) * 4;
#pragma unroll
        for (int j = 0; j < 4; ++j) {
          atomicAdd(&srep[cb + j], s[j]);
          atomicAdd(&srep[768 + cb + j], q[j]);
        }
      }
    }
  }
}

// -------- generic NT GEMM (128x128, 4 waves), 2-slot schedule --------
// OUT_ATOMIC=1: classic operand order + coalesced atomic epilogue
//   (16 consecutive cols per quarter-wave -> L2 merges lane atomics; r7's
//    swapped layout scattered atomics across 16 rows -> 4x HBM write-through)
// OUT_ATOMIC=0: swapped operands + s16x4 coalesced stores
template <int BIAS, int OUT_ATOMIC, int SUMS>
__global__ __launch_bounds__(256) void gemm_nt(
    const u16* __restrict__ A, const u16* __restrict__ B, void* __restrict__ Cv,
    const float* __restrict__ bias, float* __restrict__ sums,
    int ntiles, long lda, long ldb, long ldc, int K,
    long aBatch, long bBatch, long cBatch) {
  __shared__ u16 As[2][128 * 32];
  __shared__ u16 Bs[2][128 * 32];

  const int bm = blockIdx.x / ntiles;
  const int bn = blockIdx.x % ntiles;
  const int bb = blockIdx.y;
  const int kChunk = K / gridDim.z;
  const long k0base = (long)blockIdx.z * kChunk;
  const int nt = kChunk >> 5;

  const u16* Ab = A + (long)bb * aBatch + (long)bm * 128 * lda + k0base;
  const u16* Bb = B + (long)bb * bBatch + (long)bn * 128 * ldb + k0base;

  const int t = threadIdx.x;
  const int w = t >> 6;
  const int l = t & 63;
  const int wr = w >> 1, wc = w & 1;

  const int cg = src_chunk(l);
  const long aoff = (long)(32 * w + (l >> 2)) * lda + cg;
  const long boff = (long)(32 * w + (l >> 2)) * ldb + cg;

  f32x4 acc[4][4] = {};

  gl16(Ab + aoff, &As[0][(32 * w) * 32]);
  gl16(Ab + aoff + 16 * lda, &As[0][(32 * w + 16) * 32]);
  gl16(Bb + boff, &Bs[0][(32 * w) * 32]);
  gl16(Bb + boff + 16 * ldb, &Bs[0][(32 * w + 16) * 32]);
  if (nt > 1) {
    gl16(Ab + aoff + 32, &As[1][(32 * w) * 32]);
    gl16(Ab + aoff + 16 * lda + 32, &As[1][(32 * w + 16) * 32]);
    gl16(Bb + boff + 32, &Bs[1][(32 * w) * 32]);
    gl16(Bb + boff + 16 * ldb + 32, &Bs[1][(32 * w + 16) * 32]);
  }

  const int koff = rd_koff(l);

  for (int tt = 0; tt < nt; ++tt) {
    const int cur = tt & 1;
    if (tt + 1 < nt)
      asm volatile("s_waitcnt vmcnt(4)" ::: "memory");
    else
      asm volatile("s_waitcnt vmcnt(0)" ::: "memory");
    __builtin_amdgcn_s_barrier();

    bf16x8 af[4], bfr[4];
#pragma unroll
    for (int mi = 0; mi < 4; ++mi)
      af[mi] = __builtin_bit_cast(
          bf16x8, *(const s16x8*)(&As[cur][(wr * 64 + mi * 16 + (l & 15)) * 32 + koff]));
#pragma unroll
    for (int ni = 0; ni < 4; ++ni)
      bfr[ni] = __builtin_bit_cast(
          bf16x8, *(const s16x8*)(&Bs[cur][(wc * 64 + ni * 16 + (l & 15)) * 32 + koff]));
#pragma unroll
    for (int mi = 0; mi < 4; ++mi)
#pragma unroll
      for (int ni = 0; ni < 4; ++ni)
        acc[mi][ni] = OUT_ATOMIC
            ? __builtin_amdgcn_mfma_f32_16x16x32_bf16(af[mi], bfr[ni],
                                                      acc[mi][ni], 0, 0, 0)
            : __builtin_amdgcn_mfma_f32_16x16x32_bf16(bfr[ni], af[mi],
                                                      acc[mi][ni], 0, 0, 0);

    __builtin_amdgcn_s_barrier();
    if (tt + 2 < nt) {
      const long ko = (long)(tt + 2) * 32;
      gl16(Ab + aoff + ko, &As[cur][(32 * w) * 32]);
      gl16(Ab + aoff + 16 * lda + ko, &As[cur][(32 * w + 16) * 32]);
      gl16(Bb + boff + ko, &Bs[cur][(32 * w) * 32]);
      gl16(Bb + boff + 16 * ldb + ko, &Bs[cur][(32 * w + 16) * 32]);
    }
  }
  __builtin_amdgcn_sched_barrier(0);

  const long crow0 = (long)bm * 128 + wr * 64;
  const long ccol0 = (long)bn * 128 + wc * 64;

  if (OUT_ATOMIC) {
    // classic layout: acc[mi][ni] reg j = C[16mi+(l>>4)*4+j][16ni+(l&15)]
    float* C = (float*)Cv + (long)bb * cBatch;
#pragma unroll
    for (int mi = 0; mi < 4; ++mi)
#pragma unroll
      for (int j = 0; j < 4; ++j) {
        long row = crow0 + mi * 16 + (l >> 4) * 4 + j;
#pragma unroll
        for (int ni = 0; ni < 4; ++ni) {
          long col = ccol0 + ni * 16 + (l & 15);
          atomicAdd(&C[row * ldc + col], acc[mi][ni][j]);
        }
      }
  } else {
    // swapped layout: acc[mi][ni] reg j = C[16mi+(l&15)][16ni+(l>>4)*4+j]
    u16* C = (u16*)Cv + (long)bb * cBatch;
#pragma unroll
    for (int mi = 0; mi < 4; ++mi) {
      long row = crow0 + mi * 16 + (l & 15);
      float rb = (BIAS == 1) ? bias[row] : 0.f;
      u16* Cr = C + row * ldc + ccol0 + (l >> 4) * 4;
#pragma unroll
      for (int ni = 0; ni < 4; ++ni) {
        f32x4 cbv = {};
        if (BIAS == 2)
          cbv = *(const f32x4*)(bias + ccol0 + ni * 16 + (l >> 4) * 4);
        s16x4 v;
#pragma unroll
        for (int j = 0; j < 4; ++j)
          v[j] = (short)f2bf(acc[mi][ni][j] + rb + cbv[j]);
        *(s16x4*)(Cr + ni * 16) = v;
      }
    }
  }

  if (SUMS && !OUT_ATOMIC) {
    float* srep = sums + (blockIdx.x & 7) * 1536;
#pragma unroll
    for (int ni = 0; ni < 4; ++ni) {
      f32x4 s = {}, q = {};
#pragma unroll
      for (int mi = 0; mi < 4; ++mi)
#pragma unroll
        for (int j = 0; j < 4; ++j) {
          float v = acc[mi][ni][j];
          s[j] += v;
          q[j] += v * v;
        }
#pragma unroll
      for (int m = 1; m < 16; m <<= 1) {
#pragma unroll
        for (int j = 0; j < 4; ++j) {
          s[j] += __shfl_xor(s[j], m);
          q[j] += __shfl_xor(q[j], m);
        }
      }
      if ((l & 15) == 0) {
        long cb = ccol0 + ni * 16 + (l >> 4) * 4;
#pragma unroll
        for (int j = 0; j < 4; ++j) {
          atomicAdd(&srep[cb + j], s[j]);
          atomicAdd(&srep[768 + cb + j], q[j]);
        }
      }
    }
  }
}

// ---------------- BN ----------------
__global__ void bn_stats(const float* __restrict__ sums, const float* __restrict__ gamma,
                         const float* __restrict__ beta, float* __restrict__ stats,
                         float invN) {
  int c = threadIdx.x;
  float s = 0.f, q = 0.f;
#pragma unroll
  for (int r = 0; r < 8; ++r) {
    s += sums[r * 1536 + c];
    q += sums[r * 1536 + 768 + c];
  }
  float mu = s * invN;
  float var = q * invN - mu * mu;
  float sc = gamma[c] * rsqrtf(var + 1e-5f);
  stats[c] = sc;
  stats[768 + c] = beta[c] - mu * sc;
}

template <int OUT_F32>
__global__ void bn_apply(const u16* __restrict__ pre, const u16* __restrict__ resid,
                         const float* __restrict__ stats, void* __restrict__ out,
                         long n8) {
  long stride = (long)gridDim.x * blockDim.x;
  for (long i = (long)blockIdx.x * blockDim.x + threadIdx.x; i < n8; i += stride) {
    long base = i * 8;
    int c = (int)(base % 768);
    f32x4 sc0 = *(const f32x4*)(stats + c);
    f32x4 sc1 = *(const f32x4*)(stats + c + 4);
    f32x4 sh0 = *(const f32x4*)(stats + 768 + c);
    f32x4 sh1 = *(const f32x4*)(stats + 768 + c + 4);
    s16x8 p = *(const s16x8*)(pre + base);
    s16x8 rv = *(const s16x8*)(resid + base);
    float o[8];
#pragma unroll
    for (int j = 0; j < 4; ++j)
      o[j] = bf2f((u16)p[j]) * sc0[j] + sh0[j] + bf2f((u16)rv[j]);
#pragma unroll
    for (int j = 0; j < 4; ++j)
      o[4 + j] = bf2f((u16)p[4 + j]) * sc1[j] + sh1[j] + bf2f((u16)rv[4 + j]);
    if (OUT_F32) {
      f32x4 o0, o1;
#pragma unroll
      for (int j = 0; j < 4; ++j) { o0[j] = o[j]; o1[j] = o[4 + j]; }
      f32x4* op = (f32x4*)((float*)out + base);
      op[0] = o0;
      op[1] = o1;
    } else {
      s16x8 ov;
#pragma unroll
      for (int j = 0; j < 8; ++j) ov[j] = (short)f2bf(o[j]);
      *(s16x8*)((u16*)out + base) = ov;
    }
  }
}

extern "C" void kernel_launch(void* const* d_in, const int* in_sizes, int n_in,
                              void* d_out, int out_size, void* d_ws, size_t ws_size,
                              hipStream_t stream) {
  const float* x = (const float*)d_in[0];
  const float* x0 = (const float*)d_in[1];
  const float* c_wg = (const float*)d_in[2];
  const float* c_bg = (const float*)d_in[3];
  const float* c_wt = (const float*)d_in[4];
  const float* c_bt = (const float*)d_in[5];
  const float* c_wp = (const float*)d_in[6];
  const float* c_bp = (const float*)d_in[7];
  const float* c_ww = (const float*)d_in[8];
  const float* c_gamma = (const float*)d_in[10];
  const float* c_beta = (const float*)d_in[11];
  const float* p_wg = (const float*)d_in[12];
  const float* p_bg = (const float*)d_in[13];
  const float* p_wt = (const float*)d_in[14];
  const float* p_bt = (const float*)d_in[15];
  const float* p_wp = (const float*)d_in[16];
  const float* p_bp = (const float*)d_in[17];
  const float* p_ww = (const float*)d_in[18];
  const float* p_gamma = (const float*)d_in[20];
  const float* p_beta = (const float*)d_in[21];

  char* ws = (char*)d_ws;
  const long NT = 32768;
  u16* xbf = (u16*)(ws + 0);
  u16* x0bf = (u16*)(ws + 50331648);
  u16* th = (u16*)(ws + 50331648);
  float* kvf_c = (float*)(ws + 75497472);
  float* kvf_p = (float*)(ws + 80216064);
  u16* kvb = (u16*)(ws + 82313216);
  u16* kvwT = (u16*)(ws + 84672512);
  u16* gphT = (u16*)(ws + 100663296);
  u16* wcat = (u16*)(ws + 184549376);
  u16* wt_c = (u16*)(ws + 186515456);
  u16* wt_p = (u16*)(ws + 187105280);
  u16* ww_c = (u16*)(ws + 187498496);
  u16* ww_p = (u16*)(ws + 188088320);
  float* biasb = (float*)(ws + 188481536);
  float* sums = (float*)(ws + 188489216);   // 2 x 8 x 1536 floats
  float* stats = (float*)(ws + 188587520);  // 1536 floats
  u16* zbf = xbf;
  u16* pre = gphT;

  // ---- prep ----
  cvt_in2<<<4096, 256, 0, stream>>>(x, x0, xbf, x0bf, NT * 768 / 8);
  prep_w<<<480, 256, 0, stream>>>(c_wg, c_wp, p_wg, p_wp, c_wt, p_wt, c_ww, p_ww,
                                  wcat, wt_c, wt_p, ww_c, ww_p);
  prep_b<<<104, 256, 0, stream>>>(c_bg, c_bp, p_bg, p_bp, c_bt, p_bt, biasb, sums);

  // ---- fused gphT[1280][32768] = Wcat @ x0^T (+row bias) ----
  gemm_nt_big<1, 0><<<dim3(5 * 128, 1, 1), 512, 0, stream>>>(
      wcat, x0bf, gphT, biasb, nullptr, 128, 768, 768, 32768, 768, 0, 0, 0);
  hipMemsetAsync(kvf_c, 0, 4718592 + 2097152, stream);

  // ================= CNL (D=384) =================
  gemm_nt<2, 0, 0><<<dim3(256 * 3, 1, 1), 256, 0, stream>>>(
      xbf, wt_c, th, biasb + 1280, nullptr, 3, 768, 768, 384, 768, 0, 0, 0);
  gemm_nt<0, 1, 0><<<dim3(9, 8, 8), 256, 0, stream>>>(
      gphT + (long)384 * 32768, gphT, kvf_c, nullptr, nullptr, 3, 32768, 32768,
      384, 4096, 4096, 4096, (long)384 * 384);
  cvt_flat8<<<576, 256, 0, stream>>>(kvf_c, kvb, (long)8 * 384 * 384 / 8, 1.f / 4096.f);
  gemm_nt<0, 0, 0><<<dim3(18, 8, 1), 256, 0, stream>>>(
      ww_c, kvb, kvwT, nullptr, nullptr, 3, 384, 384, 384, 384, 0,
      (long)384 * 384, (long)768 * 384);
  gemm_nt_big<0, 1><<<dim3(48, 8, 1), 512, 0, stream>>>(
      th, kvwT, pre, nullptr, sums, 3, 384, 384, 768, 384, (long)4096 * 384,
      (long)768 * 384, (long)4096 * 768);
  bn_stats<<<1, 768, 0, stream>>>(sums, c_gamma, c_beta, stats, 1.f / 32768.f);
  bn_apply<0><<<2048, 256, 0, stream>>>(pre, xbf, stats, zbf, NT * 768 / 8);

  // ================= PNL (D=192, padded to 256) =================
  gemm_nt<2, 0, 0><<<dim3(256 * 2, 1, 1), 256, 0, stream>>>(
      zbf, wt_p, th, biasb + 1664, nullptr, 2, 768, 768, 256, 768, 0, 0, 0);
  gemm_nt<0, 1, 0><<<dim3(4, 8, 8), 256, 0, stream>>>(
      gphT + (long)1024 * 32768, gphT + (long)768 * 32768, kvf_p, nullptr, nullptr,
      2, 32768, 32768, 256, 4096, 4096, 4096, (long)256 * 256);
  cvt_flat8<<<256, 256, 0, stream>>>(kvf_p, kvb, (long)8 * 256 * 256 / 8, 1.f / 4096.f);
  gemm_nt<0, 0, 0><<<dim3(12, 8, 1), 256, 0, stream>>>(
      ww_p, kvb, kvwT, nullptr, nullptr, 2, 256, 256, 256, 256, 0,
      (long)256 * 256, (long)768 * 256);
  gemm_nt_big<0, 1><<<dim3(48, 8, 1), 512, 0, stream>>>(
      th, kvwT, pre, nullptr, sums + 8 * 1536, 3, 256, 256, 768, 256,
      (long)4096 * 256, (long)768 * 256, (long)4096 * 768);
  bn_stats<<<1, 768, 0, stream>>>(sums + 8 * 1536, p_gamma, p_beta, stats, 1.f / 32768.f);
  bn_apply<1><<<2048, 256, 0, stream>>>(pre, zbf, stats, (float*)d_out, NT * 768 / 8);
}

// Round 9
// 455.730 us; speedup vs baseline: 1.3627x; 1.0668x over previous
//
#include <hip/hip_runtime.h>
#include <stdint.h>

typedef unsigned short u16;
typedef __bf16 bf16x8 __attribute__((ext_vector_type(8)));
typedef short s16x8 __attribute__((ext_vector_type(8)));
typedef short s16x4 __attribute__((ext_vector_type(4)));
typedef float f32x4 __attribute__((ext_vector_type(4)));

__device__ __forceinline__ u16 f2bf(float f) {
  uint32_t u = __builtin_bit_cast(uint32_t, f);
  u += 0x7fffu + ((u >> 16) & 1u);
  return (u16)(u >> 16);
}
__device__ __forceinline__ float bf2f(u16 h) {
  uint32_t u = ((uint32_t)h) << 16;
  return __builtin_bit_cast(float, u);
}

// async global->LDS, 16B per lane, wave-uniform LDS base + lane*16
__device__ __forceinline__ void gl16(const u16* g, u16* l) {
  __builtin_amdgcn_global_load_lds(
      (const __attribute__((address_space(1))) void*)g,
      (__attribute__((address_space(3))) void*)l, 16, 0, 0);
}

// s_barrier that is also a compiler memory fence
__device__ __forceinline__ void barf() {
  asm volatile("s_barrier" ::: "memory");
}

// ---- T2 LDS XOR-swizzle (verified r5: bank conflicts -> 0) ----
__device__ __forceinline__ int src_chunk(int l) {
  return (((l & 3) ^ ((l >> 3) & 3)) * 8);
}
__device__ __forceinline__ int rd_koff(int l) {
  return (((l >> 4) ^ (((l & 15) >> 1) & 3)) * 8);
}

// ---------------- input converts ----------------
__global__ void cvt_in2(const float* __restrict__ a, const float* __restrict__ b,
                        u16* __restrict__ da, u16* __restrict__ db, long n8each) {
  long stride = (long)gridDim.x * blockDim.x;
  long total = 2 * n8each;
  for (long i = (long)blockIdx.x * blockDim.x + threadIdx.x; i < total; i += stride) {
    const float* src = (i < n8each) ? a + i * 8 : b + (i - n8each) * 8;
    u16* dst = (i < n8each) ? da + i * 8 : db + (i - n8each) * 8;
    const f32x4* s = (const f32x4*)src;
    f32x4 v0 = s[0], v1 = s[1];
    s16x8 o;
#pragma unroll
    for (int j = 0; j < 4; ++j) o[j] = (short)f2bf(v0[j]);
#pragma unroll
    for (int j = 0; j < 4; ++j) o[4 + j] = (short)f2bf(v1[j]);
    *(s16x8*)dst = o;
  }
}

__global__ void cvt_flat8(const float* __restrict__ src, u16* __restrict__ dst,
                          long n8, float scale) {
  long stride = (long)gridDim.x * blockDim.x;
  for (long i = (long)blockIdx.x * blockDim.x + threadIdx.x; i < n8; i += stride) {
    const f32x4* s = (const f32x4*)(src + i * 8);
    f32x4 a = s[0], b = s[1];
    s16x8 o;
#pragma unroll
    for (int j = 0; j < 4; ++j) o[j] = (short)f2bf(a[j] * scale);
#pragma unroll
    for (int j = 0; j < 4; ++j) o[4 + j] = (short)f2bf(b[j] * scale);
    *(s16x8*)(dst + i * 8) = o;
  }
}

// ---------------- weight prep ----------------
__global__ void prep_w(const float* __restrict__ c_wg, const float* __restrict__ c_wp,
                       const float* __restrict__ p_wg, const float* __restrict__ p_wp,
                       const float* __restrict__ c_wt, const float* __restrict__ p_wt,
                       const float* __restrict__ c_ww, const float* __restrict__ p_ww,
                       u16* __restrict__ wcat, u16* __restrict__ wt_c,
                       u16* __restrict__ wt_p, u16* __restrict__ ww_c,
                       u16* __restrict__ ww_p) {
  const int C0 = 1280 * 768 / 4;
  const int C1 = C0 + 384 * 768 / 4;
  const int C2 = C1 + 256 * 768 / 4;
  const int C3 = C2 + 768 * 384 / 4;
  const int C4 = C3 + 768 * 256 / 4;
  int stride = gridDim.x * blockDim.x;
  for (int i = blockIdx.x * blockDim.x + threadIdx.x; i < C4; i += stride) {
    const float* src = nullptr;
    u16* dst;
    if (i < C0) {
      int e = i * 4;
      dst = wcat + e;
      int r = e / 768;
      if (r < 384) src = c_wg + e;
      else if (r < 768) src = c_wp + e - 384 * 768;
      else if (r < 960) src = p_wg + e - 768 * 768;
      else if (r < 1024) src = nullptr;
      else if (r < 1216) src = p_wp + e - 1024 * 768;
      else src = nullptr;
    } else if (i < C1) {
      int e = (i - C0) * 4; dst = wt_c + e; src = c_wt + e;
    } else if (i < C2) {
      int e = (i - C1) * 4; dst = wt_p + e;
      src = (e / 768 < 192) ? p_wt + e : nullptr;
    } else if (i < C3) {
      int e = (i - C2) * 4; dst = ww_c + e; src = c_ww + e;
    } else {
      int e = (i - C3) * 4; dst = ww_p + e;
      int r = e >> 8, c = e & 255;
      src = (c < 192) ? p_ww + r * 192 + c : nullptr;
    }
    s16x4 o;
    if (src) {
      f32x4 v = *(const f32x4*)src;
#pragma unroll
      for (int j = 0; j < 4; ++j) o[j] = (short)f2bf(v[j]);
    } else {
      o = s16x4{0, 0, 0, 0};
    }
    *(s16x4*)dst = o;
  }
}

// biasb[1920] + zero sums[0..24575] (2 x 8 replicas x 1536)
__global__ void prep_b(const float* __restrict__ c_bg, const float* __restrict__ c_bp,
                       const float* __restrict__ p_bg, const float* __restrict__ p_bp,
                       const float* __restrict__ c_bt, const float* __restrict__ p_bt,
                       float* __restrict__ biasb, float* __restrict__ sums) {
  int i = blockIdx.x * blockDim.x + threadIdx.x;
  if (i < 1920) {
    float v = 0.f;
    if (i < 384) v = c_bg[i];
    else if (i < 768) v = c_bp[i - 384];
    else if (i < 960) v = p_bg[i - 768];
    else if (i < 1024) v = 0.f;
    else if (i < 1216) v = p_bp[i - 1024];
    else if (i < 1280) v = 0.f;
    else if (i < 1664) v = c_bt[i - 1280];
    else if (i < 1856) v = p_bt[i - 1664];
    biasb[i] = v;
  } else if (i < 1920 + 24576) {
    sums[i - 1920] = 0.f;
  }
}

// ======== big NT GEMM: 256x256, BK=32, 8 waves, 4-slot ring, PAIR loop ========
// r5 schedule generalized to tile-pairs: one barrier-pair per 2 K-tiles.
// Requires nt even and >= 4 (all call sites: 8, 12, 24).
// Classic layout: acc[mi][ni] reg j = C[16mi+(l>>4)*4+j][16ni+(l&15)]
template <int BIAS, int SUMS>
__global__ __launch_bounds__(512) void gemm_nt_big(
    const u16* __restrict__ A, const u16* __restrict__ B, void* __restrict__ Cv,
    const float* __restrict__ bias, float* __restrict__ sums,
    int ntiles, long lda, long ldb, long ldc, int K,
    long aBatch, long bBatch, long cBatch) {
  __shared__ u16 As[4][256 * 32];
  __shared__ u16 Bs[4][256 * 32];

  const int bm = blockIdx.x / ntiles;
  const int bn = blockIdx.x % ntiles;
  const int bb = blockIdx.y;
  const int nt = K >> 5;

  const u16* Ab = A + (long)bb * aBatch + (long)bm * 256 * lda;
  const u16* Bb = B + (long)bb * bBatch + (long)bn * 256 * ldb;

  const int t = threadIdx.x;
  const int w = t >> 6;
  const int l = t & 63;
  const int wr = w >> 2;
  const int wc = w & 3;

  const int srow = w * 16 + (l >> 2);
  const int cg = src_chunk(l);
  const long aoff0 = (long)srow * lda + cg;
  const long aoff1 = (long)(128 + srow) * lda + cg;
  const long boff0 = (long)srow * ldb + cg;
  const long boff1 = (long)(128 + srow) * ldb + cg;

#define STAGE_A(T, BUF)                                   \
  gl16(Ab + aoff0 + (long)(T) * 32, &As[BUF][w * 512]);   \
  gl16(Ab + aoff1 + (long)(T) * 32, &As[BUF][(8 + w) * 512]);
#define STAGE_B(T, BUF)                                   \
  gl16(Bb + boff0 + (long)(T) * 32, &Bs[BUF][w * 512]);   \
  gl16(Bb + boff1 + (long)(T) * 32, &Bs[BUF][(8 + w) * 512]);

  f32x4 acc[8][4] = {};

  // prologue: stage tiles 0..3 into slots 0..3 (16 loads/wave)
  STAGE_A(0, 0); STAGE_B(0, 0);
  STAGE_A(1, 1); STAGE_B(1, 1);
  STAGE_A(2, 2); STAGE_B(2, 2);
  STAGE_A(3, 3); STAGE_B(3, 3);

  const int koff = rd_koff(l);
  const int ar = wr * 128 + (l & 15);
  const int br = wc * 64 + (l & 15);

  for (int tt = 0; tt < nt; tt += 2) {
    // pair (tt, tt+1) staged; (tt+2, tt+3) may remain in flight (8 loads)
    if (tt + 4 <= nt) asm volatile("s_waitcnt vmcnt(8)" ::: "memory");
    else              asm volatile("s_waitcnt vmcnt(0)" ::: "memory");
    barf();

    const int c0 = tt & 3;
    const int c1 = (tt + 1) & 3;

    // tile tt
    {
      bf16x8 bfr[4], af[8];
#pragma unroll
      for (int ni = 0; ni < 4; ++ni)
        bfr[ni] = __builtin_bit_cast(
            bf16x8, *(const s16x8*)(&Bs[c0][(br + ni * 16) * 32 + koff]));
#pragma unroll
      for (int mi = 0; mi < 8; ++mi)
        af[mi] = __builtin_bit_cast(
            bf16x8, *(const s16x8*)(&As[c0][(ar + mi * 16) * 32 + koff]));
      __builtin_amdgcn_s_setprio(1);
#pragma unroll
      for (int mi = 0; mi < 8; ++mi)
#pragma unroll
        for (int ni = 0; ni < 4; ++ni)
          acc[mi][ni] = __builtin_amdgcn_mfma_f32_16x16x32_bf16(
              af[mi], bfr[ni], acc[mi][ni], 0, 0, 0);
      __builtin_amdgcn_s_setprio(0);
    }
    // tile tt+1 (no barrier between: compiler interleaves these ds_reads
    // with the previous MFMA cluster)
    {
      bf16x8 bfr[4], af[8];
#pragma unroll
      for (int ni = 0; ni < 4; ++ni)
        bfr[ni] = __builtin_bit_cast(
            bf16x8, *(const s16x8*)(&Bs[c1][(br + ni * 16) * 32 + koff]));
#pragma unroll
      for (int mi = 0; mi < 8; ++mi)
        af[mi] = __builtin_bit_cast(
            bf16x8, *(const s16x8*)(&As[c1][(ar + mi * 16) * 32 + koff]));
      __builtin_amdgcn_s_setprio(1);
#pragma unroll
      for (int mi = 0; mi < 8; ++mi)
#pragma unroll
        for (int ni = 0; ni < 4; ++ni)
          acc[mi][ni] = __builtin_amdgcn_mfma_f32_16x16x32_bf16(
              af[mi], bfr[ni], acc[mi][ni], 0, 0, 0);
      __builtin_amdgcn_s_setprio(0);
    }

    barf();  // all waves done reading slots c0,c1
    if (tt + 4 < nt) {  // restage freed slots with pair (tt+4, tt+5)
      STAGE_A(tt + 4, c0); STAGE_B(tt + 4, c0);
      STAGE_A(tt + 5, c1); STAGE_B(tt + 5, c1);
    }
  }
#undef STAGE_A
#undef STAGE_B
  __builtin_amdgcn_sched_barrier(0);

  const long crow0 = (long)bm * 256 + wr * 128;
  const long ccol0 = (long)bn * 256 + wc * 64;
  u16* C = (u16*)Cv + (long)bb * cBatch;
#pragma unroll
  for (int mi = 0; mi < 8; ++mi)
#pragma unroll
    for (int j = 0; j < 4; ++j) {
      long row = crow0 + mi * 16 + (l >> 4) * 4 + j;
      float rb = (BIAS == 1) ? bias[row] : 0.f;
#pragma unroll
      for (int ni = 0; ni < 4; ++ni) {
        long col = ccol0 + ni * 16 + (l & 15);
        C[row * ldc + col] = f2bf(acc[mi][ni][j] + rb);
      }
    }

  if (SUMS) {
    float* srep = sums + (blockIdx.x & 7) * 1536;
#pragma unroll
    for (int ni = 0; ni < 4; ++ni) {
      float s = 0.f, q = 0.f;
#pragma unroll
      for (int mi = 0; mi < 8; ++mi)
#pragma unroll
        for (int j = 0; j < 4; ++j) {
          float v = acc[mi][ni][j];
          s += v;
          q += v * v;
        }
      s += __shfl_xor(s, 16);
      q += __shfl_xor(q, 16);
      s += __shfl_xor(s, 32);
      q += __shfl_xor(q, 32);
      if (l < 16) {
        long col = ccol0 + ni * 16 + l;
        atomicAdd(&srep[col], s);
        atomicAdd(&srep[768 + col], q);
      }
    }
  }
}

// -------- generic NT GEMM (128x128, 4 waves): r5-exact --------
template <int BIAS, int OUT_ATOMIC, int SUMS>
__global__ __launch_bounds__(256) void gemm_nt(
    const u16* __restrict__ A, const u16* __restrict__ B, void* __restrict__ Cv,
    const float* __restrict__ bias, float* __restrict__ sums,
    int ntiles, long lda, long ldb, long ldc, int K,
    long aBatch, long bBatch, long cBatch) {
  __shared__ u16 As[2][128 * 32];
  __shared__ u16 Bs[2][128 * 32];

  const int bm = blockIdx.x / ntiles;
  const int bn = blockIdx.x % ntiles;
  const int bb = blockIdx.y;
  const int kChunk = K / gridDim.z;
  const long k0base = (long)blockIdx.z * kChunk;
  const int nt = kChunk >> 5;

  const u16* Ab = A + (long)bb * aBatch + (long)bm * 128 * lda + k0base;
  const u16* Bb = B + (long)bb * bBatch + (long)bn * 128 * ldb + k0base;

  const int t = threadIdx.x;
  const int w = t >> 6;
  const int l = t & 63;
  const int wr = w >> 1, wc = w & 1;

  const int cg = src_chunk(l);
  const long aoff = (long)(32 * w + (l >> 2)) * lda + cg;
  const long boff = (long)(32 * w + (l >> 2)) * ldb + cg;

  f32x4 acc[4][4] = {};

  gl16(Ab + aoff, &As[0][(32 * w) * 32]);
  gl16(Ab + aoff + 16 * lda, &As[0][(32 * w + 16) * 32]);
  gl16(Bb + boff, &Bs[0][(32 * w) * 32]);
  gl16(Bb + boff + 16 * ldb, &Bs[0][(32 * w + 16) * 32]);
  if (nt > 1) {
    gl16(Ab + aoff + 32, &As[1][(32 * w) * 32]);
    gl16(Ab + aoff + 16 * lda + 32, &As[1][(32 * w + 16) * 32]);
    gl16(Bb + boff + 32, &Bs[1][(32 * w) * 32]);
    gl16(Bb + boff + 16 * ldb + 32, &Bs[1][(32 * w + 16) * 32]);
  }

  const int koff = rd_koff(l);

  for (int tt = 0; tt < nt; ++tt) {
    const int cur = tt & 1;
    if (tt + 1 < nt)
      asm volatile("s_waitcnt vmcnt(4)" ::: "memory");
    else
      asm volatile("s_waitcnt vmcnt(0)" ::: "memory");
    __builtin_amdgcn_s_barrier();

    bf16x8 af[4], bfr[4];
#pragma unroll
    for (int mi = 0; mi < 4; ++mi)
      af[mi] = __builtin_bit_cast(
          bf16x8, *(const s16x8*)(&As[cur][(wr * 64 + mi * 16 + (l & 15)) * 32 + koff]));
#pragma unroll
    for (int ni = 0; ni < 4; ++ni)
      bfr[ni] = __builtin_bit_cast(
          bf16x8, *(const s16x8*)(&Bs[cur][(wc * 64 + ni * 16 + (l & 15)) * 32 + koff]));
#pragma unroll
    for (int mi = 0; mi < 4; ++mi)
#pragma unroll
      for (int ni = 0; ni < 4; ++ni)
        acc[mi][ni] = __builtin_amdgcn_mfma_f32_16x16x32_bf16(
            af[mi], bfr[ni], acc[mi][ni], 0, 0, 0);

    __builtin_amdgcn_s_barrier();
    if (tt + 2 < nt) {
      const long ko = (long)(tt + 2) * 32;
      gl16(Ab + aoff + ko, &As[cur][(32 * w) * 32]);
      gl16(Ab + aoff + 16 * lda + ko, &As[cur][(32 * w + 16) * 32]);
      gl16(Bb + boff + ko, &Bs[cur][(32 * w) * 32]);
      gl16(Bb + boff + 16 * ldb + ko, &Bs[cur][(32 * w + 16) * 32]);
    }
  }
  __builtin_amdgcn_sched_barrier(0);

  const long crow0 = (long)bm * 128 + wr * 64;
  const long ccol0 = (long)bn * 128 + wc * 64;

  if (OUT_ATOMIC) {
    float* C = (float*)Cv + (long)bb * cBatch;
#pragma unroll
    for (int mi = 0; mi < 4; ++mi)
#pragma unroll
      for (int j = 0; j < 4; ++j) {
        long row = crow0 + mi * 16 + (l >> 4) * 4 + j;
#pragma unroll
        for (int ni = 0; ni < 4; ++ni) {
          long col = ccol0 + ni * 16 + (l & 15);
          atomicAdd(&C[row * ldc + col], acc[mi][ni][j]);
        }
      }
  } else {
    u16* C = (u16*)Cv + (long)bb * cBatch;
#pragma unroll
    for (int mi = 0; mi < 4; ++mi)
#pragma unroll
      for (int j = 0; j < 4; ++j) {
        long row = crow0 + mi * 16 + (l >> 4) * 4 + j;
        float rb = (BIAS == 1) ? bias[row] : 0.f;
#pragma unroll
        for (int ni = 0; ni < 4; ++ni) {
          long col = ccol0 + ni * 16 + (l & 15);
          float cb = (BIAS == 2) ? bias[col] : 0.f;
          C[row * ldc + col] = f2bf(acc[mi][ni][j] + rb + cb);
        }
      }
  }

  if (SUMS && !OUT_ATOMIC) {
    float* srep = sums + (blockIdx.x & 7) * 1536;
#pragma unroll
    for (int ni = 0; ni < 4; ++ni) {
      float s = 0.f, q = 0.f;
#pragma unroll
      for (int mi = 0; mi < 4; ++mi)
#pragma unroll
        for (int j = 0; j < 4; ++j) {
          float v = acc[mi][ni][j];
          s += v;
          q += v * v;
        }
      s += __shfl_xor(s, 16);
      q += __shfl_xor(q, 16);
      s += __shfl_xor(s, 32);
      q += __shfl_xor(q, 32);
      if (l < 16) {
        long col = ccol0 + ni * 16 + l;
        atomicAdd(&srep[col], s);
        atomicAdd(&srep[768 + col], q);
      }
    }
  }
}

// ---------------- BN ----------------
__global__ void bn_stats(const float* __restrict__ sums, const float* __restrict__ gamma,
                         const float* __restrict__ beta, float* __restrict__ stats,
                         float invN) {
  int c = threadIdx.x;
  float s = 0.f, q = 0.f;
#pragma unroll
  for (int r = 0; r < 8; ++r) {
    s += sums[r * 1536 + c];
    q += sums[r * 1536 + 768 + c];
  }
  float mu = s * invN;
  float var = q * invN - mu * mu;
  float sc = gamma[c] * rsqrtf(var + 1e-5f);
  stats[c] = sc;
  stats[768 + c] = beta[c] - mu * sc;
}

template <int OUT_F32>
__global__ void bn_apply(const u16* __restrict__ pre, const u16* __restrict__ resid,
                         const float* __restrict__ stats, void* __restrict__ out,
                         long n8) {
  long stride = (long)gridDim.x * blockDim.x;
  for (long i = (long)blockIdx.x * blockDim.x + threadIdx.x; i < n8; i += stride) {
    long base = i * 8;
    int c = (int)(base % 768);
    f32x4 sc0 = *(const f32x4*)(stats + c);
    f32x4 sc1 = *(const f32x4*)(stats + c + 4);
    f32x4 sh0 = *(const f32x4*)(stats + 768 + c);
    f32x4 sh1 = *(const f32x4*)(stats + 768 + c + 4);
    s16x8 p = *(const s16x8*)(pre + base);
    s16x8 rv = *(const s16x8*)(resid + base);
    float o[8];
#pragma unroll
    for (int j = 0; j < 4; ++j)
      o[j] = bf2f((u16)p[j]) * sc0[j] + sh0[j] + bf2f((u16)rv[j]);
#pragma unroll
    for (int j = 0; j < 4; ++j)
      o[4 + j] = bf2f((u16)p[4 + j]) * sc1[j] + sh1[j] + bf2f((u16)rv[4 + j]);
    if (OUT_F32) {
      f32x4 o0, o1;
#pragma unroll
      for (int j = 0; j < 4; ++j) { o0[j] = o[j]; o1[j] = o[4 + j]; }
      f32x4* op = (f32x4*)((float*)out + base);
      op[0] = o0;
      op[1] = o1;
    } else {
      s16x8 ov;
#pragma unroll
      for (int j = 0; j < 8; ++j) ov[j] = (short)f2bf(o[j]);
      *(s16x8*)((u16*)out + base) = ov;
    }
  }
}

extern "C" void kernel_launch(void* const* d_in, const int* in_sizes, int n_in,
                              void* d_out, int out_size, void* d_ws, size_t ws_size,
                              hipStream_t stream) {
  const float* x = (const float*)d_in[0];
  const float* x0 = (const float*)d_in[1];
  const float* c_wg = (const float*)d_in[2];
  const float* c_bg = (const float*)d_in[3];
  const float* c_wt = (const float*)d_in[4];
  const float* c_bt = (const float*)d_in[5];
  const float* c_wp = (const float*)d_in[6];
  const float* c_bp = (const float*)d_in[7];
  const float* c_ww = (const float*)d_in[8];
  const float* c_gamma = (const float*)d_in[10];
  const float* c_beta = (const float*)d_in[11];
  const float* p_wg = (const float*)d_in[12];
  const float* p_bg = (const float*)d_in[13];
  const float* p_wt = (const float*)d_in[14];
  const float* p_bt = (const float*)d_in[15];
  const float* p_wp = (const float*)d_in[16];
  const float* p_bp = (const float*)d_in[17];
  const float* p_ww = (const float*)d_in[18];
  const float* p_gamma = (const float*)d_in[20];
  const float* p_beta = (const float*)d_in[21];

  char* ws = (char*)d_ws;
  const long NT = 32768;
  u16* xbf = (u16*)(ws + 0);
  u16* x0bf = (u16*)(ws + 50331648);
  u16* th = (u16*)(ws + 50331648);
  float* kvf_c = (float*)(ws + 75497472);
  float* kvf_p = (float*)(ws + 80216064);
  u16* kvb = (u16*)(ws + 82313216);
  u16* kvwT = (u16*)(ws + 84672512);
  u16* gphT = (u16*)(ws + 100663296);
  u16* wcat = (u16*)(ws + 184549376);
  u16* wt_c = (u16*)(ws + 186515456);
  u16* wt_p = (u16*)(ws + 187105280);
  u16* ww_c = (u16*)(ws + 187498496);
  u16* ww_p = (u16*)(ws + 188088320);
  float* biasb = (float*)(ws + 188481536);
  float* sums = (float*)(ws + 188489216);   // 2 x 8 x 1536 floats
  float* stats = (float*)(ws + 188587520);  // 1536 floats
  u16* zbf = xbf;
  u16* pre = gphT;

  // ---- prep ----
  cvt_in2<<<4096, 256, 0, stream>>>(x, x0, xbf, x0bf, NT * 768 / 8);
  prep_w<<<480, 256, 0, stream>>>(c_wg, c_wp, p_wg, p_wp, c_wt, p_wt, c_ww, p_ww,
                                  wcat, wt_c, wt_p, ww_c, ww_p);
  prep_b<<<104, 256, 0, stream>>>(c_bg, c_bp, p_bg, p_bp, c_bt, p_bt, biasb, sums);

  // ---- fused gphT[1280][32768] = Wcat @ x0^T (+row bias) ----
  gemm_nt_big<1, 0><<<dim3(5 * 128, 1, 1), 512, 0, stream>>>(
      wcat, x0bf, gphT, biasb, nullptr, 128, 768, 768, 32768, 768, 0, 0, 0);
  hipMemsetAsync(kvf_c, 0, 4718592 + 2097152, stream);

  // ================= CNL (D=384) =================
  gemm_nt<2, 0, 0><<<dim3(256 * 3, 1, 1), 256, 0, stream>>>(
      xbf, wt_c, th, biasb + 1280, nullptr, 3, 768, 768, 384, 768, 0, 0, 0);
  gemm_nt<0, 1, 0><<<dim3(9, 8, 8), 256, 0, stream>>>(
      gphT + (long)384 * 32768, gphT, kvf_c, nullptr, nullptr, 3, 32768, 32768,
      384, 4096, 4096, 4096, (long)384 * 384);
  cvt_flat8<<<576, 256, 0, stream>>>(kvf_c, kvb, (long)8 * 384 * 384 / 8, 1.f / 4096.f);
  gemm_nt<0, 0, 0><<<dim3(18, 8, 1), 256, 0, stream>>>(
      ww_c, kvb, kvwT, nullptr, nullptr, 3, 384, 384, 384, 384, 0,
      (long)384 * 384, (long)768 * 384);
  gemm_nt_big<0, 1><<<dim3(48, 8, 1), 512, 0, stream>>>(
      th, kvwT, pre, nullptr, sums, 3, 384, 384, 768, 384, (long)4096 * 384,
      (long)768 * 384, (long)4096 * 768);
  bn_stats<<<1, 768, 0, stream>>>(sums, c_gamma, c_beta, stats, 1.f / 32768.f);
  bn_apply<0><<<2048, 256, 0, stream>>>(pre, xbf, stats, zbf, NT * 768 / 8);

  // ================= PNL (D=192, padded to 256) =================
  gemm_nt<2, 0, 0><<<dim3(256 * 2, 1, 1), 256, 0, stream>>>(
      zbf, wt_p, th, biasb + 1664, nullptr, 2, 768, 768, 256, 768, 0, 0, 0);
  gemm_nt<0, 1, 0><<<dim3(4, 8, 8), 256, 0, stream>>>(
      gphT + (long)1024 * 32768, gphT + (long)768 * 32768, kvf_p, nullptr, nullptr,
      2, 32768, 32768, 256, 4096, 4096, 4096, (long)256 * 256);
  cvt_flat8<<<256, 256, 0, stream>>>(kvf_p, kvb, (long)8 * 256 * 256 / 8, 1.f / 4096.f);
  gemm_nt<0, 0, 0><<<dim3(12, 8, 1), 256, 0, stream>>>(
      ww_p, kvb, kvwT, nullptr, nullptr, 2, 256, 256, 256, 256, 0,
      (long)256 * 256, (long)768 * 256);
  gemm_nt_big<0, 1><<<dim3(48, 8, 1), 512, 0, stream>>>(
      th, kvwT, pre, nullptr, sums + 8 * 1536, 3, 256, 256, 768, 256,
      (long)4096 * 256, (long)768 * 256, (long)4096 * 768);
  bn_stats<<<1, 768, 0, stream>>>(sums + 8 * 1536, p_gamma, p_beta, stats, 1.f / 32768.f);
  bn_apply<1><<<2048, 256, 0, stream>>>(pre, zbf, stats, (float*)d_out, NT * 768 / 8);
}

// Round 10
// 434.326 us; speedup vs baseline: 1.4299x; 1.0493x over previous
//
#include <hip/hip_runtime.h>
#include <stdint.h>

typedef unsigned short u16;
typedef __bf16 bf16x8 __attribute__((ext_vector_type(8)));
typedef short s16x8 __attribute__((ext_vector_type(8)));
typedef short s16x4 __attribute__((ext_vector_type(4)));
typedef float f32x4 __attribute__((ext_vector_type(4)));

__device__ __forceinline__ u16 f2bf(float f) {
  uint32_t u = __builtin_bit_cast(uint32_t, f);
  u += 0x7fffu + ((u >> 16) & 1u);
  return (u16)(u >> 16);
}
__device__ __forceinline__ float bf2f(u16 h) {
  uint32_t u = ((uint32_t)h) << 16;
  return __builtin_bit_cast(float, u);
}

// async global->LDS, 16B per lane, wave-uniform LDS base + lane*16
__device__ __forceinline__ void gl16(const u16* g, u16* l) {
  __builtin_amdgcn_global_load_lds(
      (const __attribute__((address_space(1))) void*)g,
      (__attribute__((address_space(3))) void*)l, 16, 0, 0);
}

// s_barrier that is also a compiler memory fence
__device__ __forceinline__ void barf() {
  asm volatile("s_barrier" ::: "memory");
}

// ---- T2 LDS XOR-swizzle (verified r5: bank conflicts -> 0) ----
__device__ __forceinline__ int src_chunk(int l) {
  return (((l & 3) ^ ((l >> 3) & 3)) * 8);
}
__device__ __forceinline__ int rd_koff(int l) {
  return (((l >> 4) ^ (((l & 15) >> 1) & 3)) * 8);
}

// ---------------- input converts ----------------
__global__ void cvt_in2(const float* __restrict__ a, const float* __restrict__ b,
                        u16* __restrict__ da, u16* __restrict__ db, long n8each) {
  long stride = (long)gridDim.x * blockDim.x;
  long total = 2 * n8each;
  for (long i = (long)blockIdx.x * blockDim.x + threadIdx.x; i < total; i += stride) {
    const float* src = (i < n8each) ? a + i * 8 : b + (i - n8each) * 8;
    u16* dst = (i < n8each) ? da + i * 8 : db + (i - n8each) * 8;
    const f32x4* s = (const f32x4*)src;
    f32x4 v0 = s[0], v1 = s[1];
    s16x8 o;
#pragma unroll
    for (int j = 0; j < 4; ++j) o[j] = (short)f2bf(v0[j]);
#pragma unroll
    for (int j = 0; j < 4; ++j) o[4 + j] = (short)f2bf(v1[j]);
    *(s16x8*)dst = o;
  }
}

__global__ void cvt_flat8(const float* __restrict__ src, u16* __restrict__ dst,
                          long n8, float scale) {
  long stride = (long)gridDim.x * blockDim.x;
  for (long i = (long)blockIdx.x * blockDim.x + threadIdx.x; i < n8; i += stride) {
    const f32x4* s = (const f32x4*)(src + i * 8);
    f32x4 a = s[0], b = s[1];
    s16x8 o;
#pragma unroll
    for (int j = 0; j < 4; ++j) o[j] = (short)f2bf(a[j] * scale);
#pragma unroll
    for (int j = 0; j < 4; ++j) o[4 + j] = (short)f2bf(b[j] * scale);
    *(s16x8*)(dst + i * 8) = o;
  }
}

// ---------------- weight prep ----------------
__global__ void prep_w(const float* __restrict__ c_wg, const float* __restrict__ c_wp,
                       const float* __restrict__ p_wg, const float* __restrict__ p_wp,
                       const float* __restrict__ c_wt, const float* __restrict__ p_wt,
                       const float* __restrict__ c_ww, const float* __restrict__ p_ww,
                       u16* __restrict__ wcat, u16* __restrict__ wt_c,
                       u16* __restrict__ wt_p, u16* __restrict__ ww_c,
                       u16* __restrict__ ww_p) {
  const int C0 = 1280 * 768 / 4;
  const int C1 = C0 + 384 * 768 / 4;
  const int C2 = C1 + 256 * 768 / 4;
  const int C3 = C2 + 768 * 384 / 4;
  const int C4 = C3 + 768 * 256 / 4;
  int stride = gridDim.x * blockDim.x;
  for (int i = blockIdx.x * blockDim.x + threadIdx.x; i < C4; i += stride) {
    const float* src = nullptr;
    u16* dst;
    if (i < C0) {
      int e = i * 4;
      dst = wcat + e;
      int r = e / 768;
      if (r < 384) src = c_wg + e;
      else if (r < 768) src = c_wp + e - 384 * 768;
      else if (r < 960) src = p_wg + e - 768 * 768;
      else if (r < 1024) src = nullptr;
      else if (r < 1216) src = p_wp + e - 1024 * 768;
      else src = nullptr;
    } else if (i < C1) {
      int e = (i - C0) * 4; dst = wt_c + e; src = c_wt + e;
    } else if (i < C2) {
      int e = (i - C1) * 4; dst = wt_p + e;
      src = (e / 768 < 192) ? p_wt + e : nullptr;
    } else if (i < C3) {
      int e = (i - C2) * 4; dst = ww_c + e; src = c_ww + e;
    } else {
      int e = (i - C3) * 4; dst = ww_p + e;
      int r = e >> 8, c = e & 255;
      src = (c < 192) ? p_ww + r * 192 + c : nullptr;
    }
    s16x4 o;
    if (src) {
      f32x4 v = *(const f32x4*)src;
#pragma unroll
      for (int j = 0; j < 4; ++j) o[j] = (short)f2bf(v[j]);
    } else {
      o = s16x4{0, 0, 0, 0};
    }
    *(s16x4*)dst = o;
  }
}

// biasb[1920] + zero sums[0..24575] (2 x 8 replicas x 1536)
__global__ void prep_b(const float* __restrict__ c_bg, const float* __restrict__ c_bp,
                       const float* __restrict__ p_bg, const float* __restrict__ p_bp,
                       const float* __restrict__ c_bt, const float* __restrict__ p_bt,
                       float* __restrict__ biasb, float* __restrict__ sums) {
  int i = blockIdx.x * blockDim.x + threadIdx.x;
  if (i < 1920) {
    float v = 0.f;
    if (i < 384) v = c_bg[i];
    else if (i < 768) v = c_bp[i - 384];
    else if (i < 960) v = p_bg[i - 768];
    else if (i < 1024) v = 0.f;
    else if (i < 1216) v = p_bp[i - 1024];
    else if (i < 1280) v = 0.f;
    else if (i < 1664) v = c_bt[i - 1280];
    else if (i < 1856) v = p_bt[i - 1664];
    biasb[i] = v;
  } else if (i < 1920 + 24576) {
    sums[i - 1920] = 0.f;
  }
}

// ======== big NT GEMM: 256x256 tile, BK=32, 8 waves, 4-slot ring ========
// r5-exact 2-phase schedule (proven best: 95.3us on gphT).
// Classic layout: acc[mi][ni] reg j = C[16mi+(l>>4)*4+j][16ni+(l&15)]
template <int BIAS, int SUMS>
__global__ __launch_bounds__(512) void gemm_nt_big(
    const u16* __restrict__ A, const u16* __restrict__ B, void* __restrict__ Cv,
    const float* __restrict__ bias, float* __restrict__ sums,
    int ntiles, long lda, long ldb, long ldc, int K,
    long aBatch, long bBatch, long cBatch) {
  __shared__ u16 As[4][256 * 32];
  __shared__ u16 Bs[4][256 * 32];

  const int bm = blockIdx.x / ntiles;
  const int bn = blockIdx.x % ntiles;
  const int bb = blockIdx.y;
  const int nt = K >> 5;

  const u16* Ab = A + (long)bb * aBatch + (long)bm * 256 * lda;
  const u16* Bb = B + (long)bb * bBatch + (long)bn * 256 * ldb;

  const int t = threadIdx.x;
  const int w = t >> 6;
  const int l = t & 63;
  const int wr = w >> 2;
  const int wc = w & 3;

  const int srow = w * 16 + (l >> 2);
  const int cg = src_chunk(l);
  const long aoff0 = (long)srow * lda + cg;
  const long aoff1 = (long)(128 + srow) * lda + cg;
  const long boff0 = (long)srow * ldb + cg;
  const long boff1 = (long)(128 + srow) * ldb + cg;

#define STAGE_A(T, BUF)                                   \
  gl16(Ab + aoff0 + (long)(T) * 32, &As[BUF][w * 512]);   \
  gl16(Ab + aoff1 + (long)(T) * 32, &As[BUF][(8 + w) * 512]);
#define STAGE_B(T, BUF)                                   \
  gl16(Bb + boff0 + (long)(T) * 32, &Bs[BUF][w * 512]);   \
  gl16(Bb + boff1 + (long)(T) * 32, &Bs[BUF][(8 + w) * 512]);

  f32x4 acc[8][4] = {};

  STAGE_A(0, 0); STAGE_B(0, 0);
  if (nt > 1) { STAGE_A(1, 1); STAGE_B(1, 1); }
  if (nt > 2) { STAGE_A(2, 2); STAGE_B(2, 2); }
  if (nt > 2)      asm volatile("s_waitcnt vmcnt(8)" ::: "memory");
  else if (nt > 1) asm volatile("s_waitcnt vmcnt(4)" ::: "memory");
  else             asm volatile("s_waitcnt vmcnt(0)" ::: "memory");
  barf();

  const int koff = rd_koff(l);
  const int ar = wr * 128 + (l & 15);
  const int br = wc * 64 + (l & 15);

  for (int tt = 0; tt < nt; ++tt) {
    const int cur = tt & 3;
    const int pf = (tt + 3) & 3;
    const bool do_pf = (tt + 3) < nt;

    // ---- phase 0: B frags + A frags(m0..3); stage A of tile tt+3 ----
    bf16x8 bfr[4], af[4];
#pragma unroll
    for (int ni = 0; ni < 4; ++ni)
      bfr[ni] = __builtin_bit_cast(
          bf16x8, *(const s16x8*)(&Bs[cur][(br + ni * 16) * 32 + koff]));
#pragma unroll
    for (int mi = 0; mi < 4; ++mi)
      af[mi] = __builtin_bit_cast(
          bf16x8, *(const s16x8*)(&As[cur][(ar + mi * 16) * 32 + koff]));
    if (do_pf) { STAGE_A(tt + 3, pf); }
    barf();
    __builtin_amdgcn_s_setprio(1);
#pragma unroll
    for (int mi = 0; mi < 4; ++mi)
#pragma unroll
      for (int ni = 0; ni < 4; ++ni)
        acc[mi][ni] = __builtin_amdgcn_mfma_f32_16x16x32_bf16(
            af[mi], bfr[ni], acc[mi][ni], 0, 0, 0);
    __builtin_amdgcn_s_setprio(0);
    barf();

    // ---- phase 1: A frags(m4..7); stage B of tile tt+3 ----
    bf16x8 ag[4];
#pragma unroll
    for (int mi = 0; mi < 4; ++mi)
      ag[mi] = __builtin_bit_cast(
          bf16x8, *(const s16x8*)(&As[cur][(ar + 64 + mi * 16) * 32 + koff]));
    if (do_pf) { STAGE_B(tt + 3, pf); }
    barf();
    __builtin_amdgcn_s_setprio(1);
#pragma unroll
    for (int mi = 0; mi < 4; ++mi)
#pragma unroll
      for (int ni = 0; ni < 4; ++ni)
        acc[4 + mi][ni] = __builtin_amdgcn_mfma_f32_16x16x32_bf16(
            ag[mi], bfr[ni], acc[4 + mi][ni], 0, 0, 0);
    __builtin_amdgcn_s_setprio(0);
    if (tt + 4 <= nt)      asm volatile("s_waitcnt vmcnt(8)" ::: "memory");
    else if (tt + 3 == nt) asm volatile("s_waitcnt vmcnt(4)" ::: "memory");
    else if (tt + 2 == nt) asm volatile("s_waitcnt vmcnt(0)" ::: "memory");
    barf();
  }
#undef STAGE_A
#undef STAGE_B
  __builtin_amdgcn_sched_barrier(0);

  const long crow0 = (long)bm * 256 + wr * 128;
  const long ccol0 = (long)bn * 256 + wc * 64;
  u16* C = (u16*)Cv + (long)bb * cBatch;
#pragma unroll
  for (int mi = 0; mi < 8; ++mi)
#pragma unroll
    for (int j = 0; j < 4; ++j) {
      long row = crow0 + mi * 16 + (l >> 4) * 4 + j;
      float rb = (BIAS == 1) ? bias[row] : 0.f;
#pragma unroll
      for (int ni = 0; ni < 4; ++ni) {
        long col = ccol0 + ni * 16 + (l & 15);
        C[row * ldc + col] = f2bf(acc[mi][ni][j] + rb);
      }
    }

  if (SUMS) {
    float* srep = sums + (blockIdx.x & 7) * 1536;
#pragma unroll
    for (int ni = 0; ni < 4; ++ni) {
      float s = 0.f, q = 0.f;
#pragma unroll
      for (int mi = 0; mi < 8; ++mi)
#pragma unroll
        for (int j = 0; j < 4; ++j) {
          float v = acc[mi][ni][j];
          s += v;
          q += v * v;
        }
      s += __shfl_xor(s, 16);
      q += __shfl_xor(q, 16);
      s += __shfl_xor(s, 32);
      q += __shfl_xor(q, 32);
      if (l < 16) {
        long col = ccol0 + ni * 16 + l;
        atomicAdd(&srep[col], s);
        atomicAdd(&srep[768 + col], q);
      }
    }
  }
}

// -------- generic NT GEMM (128x128, 4 waves): r5-exact --------
template <int BIAS, int OUT_ATOMIC, int SUMS>
__global__ __launch_bounds__(256) void gemm_nt(
    const u16* __restrict__ A, const u16* __restrict__ B, void* __restrict__ Cv,
    const float* __restrict__ bias, float* __restrict__ sums,
    int ntiles, long lda, long ldb, long ldc, int K,
    long aBatch, long bBatch, long cBatch) {
  __shared__ u16 As[2][128 * 32];
  __shared__ u16 Bs[2][128 * 32];

  const int bm = blockIdx.x / ntiles;
  const int bn = blockIdx.x % ntiles;
  const int bb = blockIdx.y;
  const int kChunk = K / gridDim.z;
  const long k0base = (long)blockIdx.z * kChunk;
  const int nt = kChunk >> 5;

  const u16* Ab = A + (long)bb * aBatch + (long)bm * 128 * lda + k0base;
  const u16* Bb = B + (long)bb * bBatch + (long)bn * 128 * ldb + k0base;

  const int t = threadIdx.x;
  const int w = t >> 6;
  const int l = t & 63;
  const int wr = w >> 1, wc = w & 1;

  const int cg = src_chunk(l);
  const long aoff = (long)(32 * w + (l >> 2)) * lda + cg;
  const long boff = (long)(32 * w + (l >> 2)) * ldb + cg;

  f32x4 acc[4][4] = {};

  gl16(Ab + aoff, &As[0][(32 * w) * 32]);
  gl16(Ab + aoff + 16 * lda, &As[0][(32 * w + 16) * 32]);
  gl16(Bb + boff, &Bs[0][(32 * w) * 32]);
  gl16(Bb + boff + 16 * ldb, &Bs[0][(32 * w + 16) * 32]);
  if (nt > 1) {
    gl16(Ab + aoff + 32, &As[1][(32 * w) * 32]);
    gl16(Ab + aoff + 16 * lda + 32, &As[1][(32 * w + 16) * 32]);
    gl16(Bb + boff + 32, &Bs[1][(32 * w) * 32]);
    gl16(Bb + boff + 16 * ldb + 32, &Bs[1][(32 * w + 16) * 32]);
  }

  const int koff = rd_koff(l);

  for (int tt = 0; tt < nt; ++tt) {
    const int cur = tt & 1;
    if (tt + 1 < nt)
      asm volatile("s_waitcnt vmcnt(4)" ::: "memory");
    else
      asm volatile("s_waitcnt vmcnt(0)" ::: "memory");
    __builtin_amdgcn_s_barrier();

    bf16x8 af[4], bfr[4];
#pragma unroll
    for (int mi = 0; mi < 4; ++mi)
      af[mi] = __builtin_bit_cast(
          bf16x8, *(const s16x8*)(&As[cur][(wr * 64 + mi * 16 + (l & 15)) * 32 + koff]));
#pragma unroll
    for (int ni = 0; ni < 4; ++ni)
      bfr[ni] = __builtin_bit_cast(
          bf16x8, *(const s16x8*)(&Bs[cur][(wc * 64 + ni * 16 + (l & 15)) * 32 + koff]));
#pragma unroll
    for (int mi = 0; mi < 4; ++mi)
#pragma unroll
      for (int ni = 0; ni < 4; ++ni)
        acc[mi][ni] = __builtin_amdgcn_mfma_f32_16x16x32_bf16(
            af[mi], bfr[ni], acc[mi][ni], 0, 0, 0);

    __builtin_amdgcn_s_barrier();
    if (tt + 2 < nt) {
      const long ko = (long)(tt + 2) * 32;
      gl16(Ab + aoff + ko, &As[cur][(32 * w) * 32]);
      gl16(Ab + aoff + 16 * lda + ko, &As[cur][(32 * w + 16) * 32]);
      gl16(Bb + boff + ko, &Bs[cur][(32 * w) * 32]);
      gl16(Bb + boff + 16 * ldb + ko, &Bs[cur][(32 * w + 16) * 32]);
    }
  }
  __builtin_amdgcn_sched_barrier(0);

  const long crow0 = (long)bm * 128 + wr * 64;
  const long ccol0 = (long)bn * 128 + wc * 64;

  if (OUT_ATOMIC) {
    float* C = (float*)Cv + (long)bb * cBatch;
#pragma unroll
    for (int mi = 0; mi < 4; ++mi)
#pragma unroll
      for (int j = 0; j < 4; ++j) {
        long row = crow0 + mi * 16 + (l >> 4) * 4 + j;
#pragma unroll
        for (int ni = 0; ni < 4; ++ni) {
          long col = ccol0 + ni * 16 + (l & 15);
          atomicAdd(&C[row * ldc + col], acc[mi][ni][j]);
        }
      }
  } else {
    u16* C = (u16*)Cv + (long)bb * cBatch;
#pragma unroll
    for (int mi = 0; mi < 4; ++mi)
#pragma unroll
      for (int j = 0; j < 4; ++j) {
        long row = crow0 + mi * 16 + (l >> 4) * 4 + j;
        float rb = (BIAS == 1) ? bias[row] : 0.f;
#pragma unroll
        for (int ni = 0; ni < 4; ++ni) {
          long col = ccol0 + ni * 16 + (l & 15);
          float cb = (BIAS == 2) ? bias[col] : 0.f;
          C[row * ldc + col] = f2bf(acc[mi][ni][j] + rb + cb);
        }
      }
  }

  if (SUMS && !OUT_ATOMIC) {
    float* srep = sums + (blockIdx.x & 7) * 1536;
#pragma unroll
    for (int ni = 0; ni < 4; ++ni) {
      float s = 0.f, q = 0.f;
#pragma unroll
      for (int mi = 0; mi < 4; ++mi)
#pragma unroll
        for (int j = 0; j < 4; ++j) {
          float v = acc[mi][ni][j];
          s += v;
          q += v * v;
        }
      s += __shfl_xor(s, 16);
      q += __shfl_xor(q, 16);
      s += __shfl_xor(s, 32);
      q += __shfl_xor(q, 32);
      if (l < 16) {
        long col = ccol0 + ni * 16 + l;
        atomicAdd(&srep[col], s);
        atomicAdd(&srep[768 + col], q);
      }
    }
  }
}

// ---------------- BN ----------------
__global__ void bn_stats(const float* __restrict__ sums, const float* __restrict__ gamma,
                         const float* __restrict__ beta, float* __restrict__ stats,
                         float invN) {
  int c = threadIdx.x;
  float s = 0.f, q = 0.f;
#pragma unroll
  for (int r = 0; r < 8; ++r) {
    s += sums[r * 1536 + c];
    q += sums[r * 1536 + 768 + c];
  }
  float mu = s * invN;
  float var = q * invN - mu * mu;
  float sc = gamma[c] * rsqrtf(var + 1e-5f);
  stats[c] = sc;
  stats[768 + c] = beta[c] - mu * sc;
}

template <int OUT_F32>
__global__ void bn_apply(const u16* __restrict__ pre, const u16* __restrict__ resid,
                         const float* __restrict__ stats, void* __restrict__ out,
                         long n8) {
  long stride = (long)gridDim.x * blockDim.x;
  for (long i = (long)blockIdx.x * blockDim.x + threadIdx.x; i < n8; i += stride) {
    long base = i * 8;
    int c = (int)(base % 768);
    f32x4 sc0 = *(const f32x4*)(stats + c);
    f32x4 sc1 = *(const f32x4*)(stats + c + 4);
    f32x4 sh0 = *(const f32x4*)(stats + 768 + c);
    f32x4 sh1 = *(const f32x4*)(stats + 768 + c + 4);
    s16x8 p = *(const s16x8*)(pre + base);
    s16x8 rv = *(const s16x8*)(resid + base);
    float o[8];
#pragma unroll
    for (int j = 0; j < 4; ++j)
      o[j] = bf2f((u16)p[j]) * sc0[j] + sh0[j] + bf2f((u16)rv[j]);
#pragma unroll
    for (int j = 0; j < 4; ++j)
      o[4 + j] = bf2f((u16)p[4 + j]) * sc1[j] + sh1[j] + bf2f((u16)rv[4 + j]);
    if (OUT_F32) {
      f32x4 o0, o1;
#pragma unroll
      for (int j = 0; j < 4; ++j) { o0[j] = o[j]; o1[j] = o[4 + j]; }
      f32x4* op = (f32x4*)((float*)out + base);
      op[0] = o0;
      op[1] = o1;
    } else {
      s16x8 ov;
#pragma unroll
      for (int j = 0; j < 8; ++j) ov[j] = (short)f2bf(o[j]);
      *(s16x8*)((u16*)out + base) = ov;
    }
  }
}

extern "C" void kernel_launch(void* const* d_in, const int* in_sizes, int n_in,
                              void* d_out, int out_size, void* d_ws, size_t ws_size,
                              hipStream_t stream) {
  const float* x = (const float*)d_in[0];
  const float* x0 = (const float*)d_in[1];
  const float* c_wg = (const float*)d_in[2];
  const float* c_bg = (const float*)d_in[3];
  const float* c_wt = (const float*)d_in[4];
  const float* c_bt = (const float*)d_in[5];
  const float* c_wp = (const float*)d_in[6];
  const float* c_bp = (const float*)d_in[7];
  const float* c_ww = (const float*)d_in[8];
  const float* c_gamma = (const float*)d_in[10];
  const float* c_beta = (const float*)d_in[11];
  const float* p_wg = (const float*)d_in[12];
  const float* p_bg = (const float*)d_in[13];
  const float* p_wt = (const float*)d_in[14];
  const float* p_bt = (const float*)d_in[15];
  const float* p_wp = (const float*)d_in[16];
  const float* p_bp = (const float*)d_in[17];
  const float* p_ww = (const float*)d_in[18];
  const float* p_gamma = (const float*)d_in[20];
  const float* p_beta = (const float*)d_in[21];

  char* ws = (char*)d_ws;
  const long NT = 32768;
  u16* xbf = (u16*)(ws + 0);
  u16* x0bf = (u16*)(ws + 50331648);
  u16* th = (u16*)(ws + 50331648);
  float* kvf_c = (float*)(ws + 75497472);
  float* kvf_p = (float*)(ws + 80216064);
  u16* kvb = (u16*)(ws + 82313216);
  u16* kvwT = (u16*)(ws + 84672512);
  u16* gphT = (u16*)(ws + 100663296);
  u16* wcat = (u16*)(ws + 184549376);
  u16* wt_c = (u16*)(ws + 186515456);
  u16* wt_p = (u16*)(ws + 187105280);
  u16* ww_c = (u16*)(ws + 187498496);
  u16* ww_p = (u16*)(ws + 188088320);
  float* biasb = (float*)(ws + 188481536);
  float* sums = (float*)(ws + 188489216);   // 2 x 8 x 1536 floats
  float* stats = (float*)(ws + 188587520);  // 1536 floats
  u16* zbf = xbf;
  u16* pre = gphT;

  // ---- prep ----
  cvt_in2<<<4096, 256, 0, stream>>>(x, x0, xbf, x0bf, NT * 768 / 8);
  prep_w<<<480, 256, 0, stream>>>(c_wg, c_wp, p_wg, p_wp, c_wt, p_wt, c_ww, p_ww,
                                  wcat, wt_c, wt_p, ww_c, ww_p);
  prep_b<<<104, 256, 0, stream>>>(c_bg, c_bp, p_bg, p_bp, c_bt, p_bt, biasb, sums);

  // ---- fused gphT[1280][32768] = Wcat @ x0^T (+row bias) ----
  gemm_nt_big<1, 0><<<dim3(5 * 128, 1, 1), 512, 0, stream>>>(
      wcat, x0bf, gphT, biasb, nullptr, 128, 768, 768, 32768, 768, 0, 0, 0);
  hipMemsetAsync(kvf_c, 0, 4718592 + 2097152, stream);

  // ================= CNL (D=384) =================
  gemm_nt<2, 0, 0><<<dim3(256 * 3, 1, 1), 256, 0, stream>>>(
      xbf, wt_c, th, biasb + 1280, nullptr, 3, 768, 768, 384, 768, 0, 0, 0);
  // kv split-K = 4 (halves atomic write-through; 288 blocks co-resident)
  gemm_nt<0, 1, 0><<<dim3(9, 8, 4), 256, 0, stream>>>(
      gphT + (long)384 * 32768, gphT, kvf_c, nullptr, nullptr, 3, 32768, 32768,
      384, 4096, 4096, 4096, (long)384 * 384);
  cvt_flat8<<<576, 256, 0, stream>>>(kvf_c, kvb, (long)8 * 384 * 384 / 8, 1.f / 4096.f);
  gemm_nt<0, 0, 0><<<dim3(18, 8, 1), 256, 0, stream>>>(
      ww_c, kvb, kvwT, nullptr, nullptr, 3, 384, 384, 384, 384, 0,
      (long)384 * 384, (long)768 * 384);
  gemm_nt_big<0, 1><<<dim3(48, 8, 1), 512, 0, stream>>>(
      th, kvwT, pre, nullptr, sums, 3, 384, 384, 768, 384, (long)4096 * 384,
      (long)768 * 384, (long)4096 * 768);
  bn_stats<<<1, 768, 0, stream>>>(sums, c_gamma, c_beta, stats, 1.f / 32768.f);
  bn_apply<0><<<2048, 256, 0, stream>>>(pre, xbf, stats, zbf, NT * 768 / 8);

  // ================= PNL (D=192, padded to 256; K trimmed to 192) =================
  gemm_nt<2, 0, 0><<<dim3(256 * 2, 1, 1), 256, 0, stream>>>(
      zbf, wt_p, th, biasb + 1664, nullptr, 2, 768, 768, 256, 768, 0, 0, 0);
  gemm_nt<0, 1, 0><<<dim3(4, 8, 8), 256, 0, stream>>>(
      gphT + (long)1024 * 32768, gphT + (long)768 * 32768, kvf_p, nullptr, nullptr,
      2, 32768, 32768, 256, 4096, 4096, 4096, (long)256 * 256);
  cvt_flat8<<<256, 256, 0, stream>>>(kvf_p, kvb, (long)8 * 256 * 256 / 8, 1.f / 4096.f);
  // kvw_p: K=192 (cols 192..255 of kvb are exactly zero; strides stay 256)
  gemm_nt<0, 0, 0><<<dim3(12, 8, 1), 256, 0, stream>>>(
      ww_p, kvb, kvwT, nullptr, nullptr, 2, 256, 256, 256, 192, 0,
      (long)256 * 256, (long)768 * 256);
  // pre_p: K=192 (th cols >=192 and kvwT cols >=192 multiply zero weights)
  gemm_nt_big<0, 1><<<dim3(48, 8, 1), 512, 0, stream>>>(
      th, kvwT, pre, nullptr, sums + 8 * 1536, 3, 256, 256, 768, 192,
      (long)4096 * 256, (long)768 * 256, (long)4096 * 768);
  bn_stats<<<1, 768, 0, stream>>>(sums + 8 * 1536, p_gamma, p_beta, stats, 1.f / 32768.f);
  bn_apply<1><<<2048, 256, 0, stream>>>(pre, zbf, stats, (float*)d_out, NT * 768 / 8);
}

// Round 12
// 418.259 us; speedup vs baseline: 1.4848x; 1.0384x over previous
//
#include <hip/hip_runtime.h>
#include <stdint.h>

typedef unsigned short u16;
typedef __bf16 bf16x8 __attribute__((ext_vector_type(8)));
typedef short s16x8 __attribute__((ext_vector_type(8)));
typedef short s16x4 __attribute__((ext_vector_type(4)));
typedef float f32x4 __attribute__((ext_vector_type(4)));

__device__ __forceinline__ u16 f2bf(float f) {
  uint32_t u = __builtin_bit_cast(uint32_t, f);
  u += 0x7fffu + ((u >> 16) & 1u);
  return (u16)(u >> 16);
}
__device__ __forceinline__ float bf2f(u16 h) {
  uint32_t u = ((uint32_t)h) << 16;
  return __builtin_bit_cast(float, u);
}

// async global->LDS, 16B per lane, wave-uniform LDS base + lane*16
__device__ __forceinline__ void gl16(const u16* g, u16* l) {
  __builtin_amdgcn_global_load_lds(
      (const __attribute__((address_space(1))) void*)g,
      (__attribute__((address_space(3))) void*)l, 16, 0, 0);
}

// s_barrier that is also a compiler memory fence
__device__ __forceinline__ void barf() {
  asm volatile("s_barrier" ::: "memory");
}

// ---- T2 LDS XOR-swizzle on 64B rows (verified r5: bank conflicts -> 0) ----
__device__ __forceinline__ int src_chunk(int l) {
  return (((l & 3) ^ ((l >> 3) & 3)) * 8);
}
__device__ __forceinline__ int rd_koff(int l) {
  return (((l >> 4) ^ (((l & 15) >> 1) & 3)) * 8);
}

// ---------------- input converts ----------------
__global__ void cvt_in2(const float* __restrict__ a, const float* __restrict__ b,
                        u16* __restrict__ da, u16* __restrict__ db, long n8each) {
  long stride = (long)gridDim.x * blockDim.x;
  long total = 2 * n8each;
  for (long i = (long)blockIdx.x * blockDim.x + threadIdx.x; i < total; i += stride) {
    const float* src = (i < n8each) ? a + i * 8 : b + (i - n8each) * 8;
    u16* dst = (i < n8each) ? da + i * 8 : db + (i - n8each) * 8;
    const f32x4* s = (const f32x4*)src;
    f32x4 v0 = s[0], v1 = s[1];
    s16x8 o;
#pragma unroll
    for (int j = 0; j < 4; ++j) o[j] = (short)f2bf(v0[j]);
#pragma unroll
    for (int j = 0; j < 4; ++j) o[4 + j] = (short)f2bf(v1[j]);
    *(s16x8*)dst = o;
  }
}

__global__ void cvt_flat8(const float* __restrict__ src, u16* __restrict__ dst,
                          long n8, float scale) {
  long stride = (long)gridDim.x * blockDim.x;
  for (long i = (long)blockIdx.x * blockDim.x + threadIdx.x; i < n8; i += stride) {
    const f32x4* s = (const f32x4*)(src + i * 8);
    f32x4 a = s[0], b = s[1];
    s16x8 o;
#pragma unroll
    for (int j = 0; j < 4; ++j) o[j] = (short)f2bf(a[j] * scale);
#pragma unroll
    for (int j = 0; j < 4; ++j) o[4 + j] = (short)f2bf(b[j] * scale);
    *(s16x8*)(dst + i * 8) = o;
  }
}

// ---------------- weight prep ----------------
__global__ void prep_w(const float* __restrict__ c_wg, const float* __restrict__ c_wp,
                       const float* __restrict__ p_wg, const float* __restrict__ p_wp,
                       const float* __restrict__ c_wt, const float* __restrict__ p_wt,
                       const float* __restrict__ c_ww, const float* __restrict__ p_ww,
                       u16* __restrict__ wcat, u16* __restrict__ wt_c,
                       u16* __restrict__ wt_p, u16* __restrict__ ww_c,
                       u16* __restrict__ ww_p) {
  const int C0 = 1280 * 768 / 4;
  const int C1 = C0 + 384 * 768 / 4;
  const int C2 = C1 + 256 * 768 / 4;
  const int C3 = C2 + 768 * 384 / 4;
  const int C4 = C3 + 768 * 256 / 4;
  int stride = gridDim.x * blockDim.x;
  for (int i = blockIdx.x * blockDim.x + threadIdx.x; i < C4; i += stride) {
    const float* src = nullptr;
    u16* dst;
    if (i < C0) {
      int e = i * 4;
      dst = wcat + e;
      int r = e / 768;
      if (r < 384) src = c_wg + e;
      else if (r < 768) src = c_wp + e - 384 * 768;
      else if (r < 960) src = p_wg + e - 768 * 768;
      else if (r < 1024) src = nullptr;
      else if (r < 1216) src = p_wp + e - 1024 * 768;
      else src = nullptr;
    } else if (i < C1) {
      int e = (i - C0) * 4; dst = wt_c + e; src = c_wt + e;
    } else if (i < C2) {
      int e = (i - C1) * 4; dst = wt_p + e;
      src = (e / 768 < 192) ? p_wt + e : nullptr;
    } else if (i < C3) {
      int e = (i - C2) * 4; dst = ww_c + e; src = c_ww + e;
    } else {
      int e = (i - C3) * 4; dst = ww_p + e;
      int r = e >> 8, c = e & 255;
      src = (c < 192) ? p_ww + r * 192 + c : nullptr;
    }
    s16x4 o;
    if (src) {
      f32x4 v = *(const f32x4*)src;
#pragma unroll
      for (int j = 0; j < 4; ++j) o[j] = (short)f2bf(v[j]);
    } else {
      o = s16x4{0, 0, 0, 0};
    }
    *(s16x4*)dst = o;
  }
}

// biasb[1920] + zero sums[0..24575]
__global__ void prep_b(const float* __restrict__ c_bg, const float* __restrict__ c_bp,
                       const float* __restrict__ p_bg, const float* __restrict__ p_bp,
                       const float* __restrict__ c_bt, const float* __restrict__ p_bt,
                       float* __restrict__ biasb, float* __restrict__ sums) {
  int i = blockIdx.x * blockDim.x + threadIdx.x;
  if (i < 1920) {
    float v = 0.f;
    if (i < 384) v = c_bg[i];
    else if (i < 768) v = c_bp[i - 384];
    else if (i < 960) v = p_bg[i - 768];
    else if (i < 1024) v = 0.f;
    else if (i < 1216) v = p_bp[i - 1024];
    else if (i < 1280) v = 0.f;
    else if (i < 1664) v = c_bt[i - 1280];
    else if (i < 1856) v = p_bt[i - 1664];
    biasb[i] = v;
  } else if (i < 1920 + 24576) {
    sums[i - 1920] = 0.f;
  }
}

// ======== big NT GEMM: 256x256 tile, BK=64, 8 waves, fine 4-phase pipeline ========
// r11 + FIX: barf() after tile-entry vmcnt. vmcnt is wave-local but staging is
// distributed across waves -> every read of buf b must be barrier-ordered after
// ALL waves' waits, not just our own.
// LDS: [buf][half][kk-plane][128x32 u16] per operand; 64B rows keep r5 swizzle.
// Requires K % 64 == 0 (call sites: 768, 384, 192).
template <int BIAS, int SUMS>
__global__ __launch_bounds__(512) void gemm_nt_big(
    const u16* __restrict__ A, const u16* __restrict__ B, void* __restrict__ Cv,
    const float* __restrict__ bias, float* __restrict__ sums,
    int ntiles, long lda, long ldb, long ldc, int K,
    long aBatch, long bBatch, long cBatch) {
  __shared__ u16 As[2][2][2][4096];  // 64 KB
  __shared__ u16 Bs[2][2][2][4096];  // 64 KB

  const int bm = blockIdx.x / ntiles;
  const int bn = blockIdx.x % ntiles;
  const int bb = blockIdx.y;
  const int ntk = K >> 6;

  const u16* Ab = A + (long)bb * aBatch + (long)bm * 256 * lda;
  const u16* Bb = B + (long)bb * bBatch + (long)bn * 256 * ldb;

  const int t = threadIdx.x;
  const int w = t >> 6;   // 0..7
  const int l = t & 63;
  const int wr = w >> 2;  // M half
  const int wc = w & 3;   // N quarter

  const int cg = src_chunk(l);
  const int srow = w * 16 + (l >> 2);  // block-cooperative: wave w rows [16w,16w+16)

#define ST_A(TK, BUF, H)                                                      \
  gl16(Ab + (long)((H) * 128 + srow) * lda + (long)(TK) * 64 + cg,            \
       &As[BUF][H][0][w * 512]);                                              \
  gl16(Ab + (long)((H) * 128 + srow) * lda + (long)(TK) * 64 + 32 + cg,       \
       &As[BUF][H][1][w * 512]);
#define ST_B(TK, BUF, H)                                                      \
  gl16(Bb + (long)((H) * 128 + srow) * ldb + (long)(TK) * 64 + cg,            \
       &Bs[BUF][H][0][w * 512]);                                              \
  gl16(Bb + (long)((H) * 128 + srow) * ldb + (long)(TK) * 64 + 32 + cg,       \
       &Bs[BUF][H][1][w * 512]);

  f32x4 acc[8][4] = {};

  // prologue: A(t0), B(t0), A(t1) -- 12 loads/thread
  ST_A(0, 0, 0); ST_A(0, 0, 1);
  ST_B(0, 0, 0); ST_B(0, 0, 1);
  if (ntk > 1) { ST_A(1, 1, 0); ST_A(1, 1, 1); }

  const int ko = rd_koff(l);
  const int rr = l & 15;
  const int bloc = (wc & 1) * 64;

#define RDA(BUF, KK, MI)                                                       \
  __builtin_bit_cast(bf16x8, *(const s16x8*)(                                  \
      &As[BUF][wr][KK][((MI) * 16 + rr) * 32 + ko]))
#define RDB(BUF, KK, NI)                                                       \
  __builtin_bit_cast(bf16x8, *(const s16x8*)(                                  \
      &Bs[BUF][wc >> 1][KK][(bloc + (NI) * 16 + rr) * 32 + ko]))

  for (int kt = 0; kt < ntk; ++kt) {
    const int b = kt & 1, nb = b ^ 1;
    const bool h1 = (kt + 1 < ntk), h2 = (kt + 2 < ntk);
    // tile kt's 8 loads are oldest; A(kt+1)'s 4 (if any) stay in flight
    if (h1) asm volatile("s_waitcnt vmcnt(4)" ::: "memory");
    else    asm volatile("s_waitcnt vmcnt(0)" ::: "memory");
    barf();  // FIX: reads below touch rows staged by OTHER waves; order them
             // after every wave's vmcnt wait, not just our own.

    bf16x8 a0[4][2], a4[4][2], b0[2][2], b2[2][2];

    // ---- P0: read A m0-3 + B n0-1; stage B0(kt+1) -> nb ----
#pragma unroll
    for (int mi = 0; mi < 4; ++mi) { a0[mi][0] = RDA(b, 0, mi); a0[mi][1] = RDA(b, 1, mi); }
#pragma unroll
    for (int ni = 0; ni < 2; ++ni) { b0[ni][0] = RDB(b, 0, ni); b0[ni][1] = RDB(b, 1, ni); }
    if (h1) { ST_B(kt + 1, nb, 0); }
    barf();
    __builtin_amdgcn_s_setprio(1);
#pragma unroll
    for (int mi = 0; mi < 4; ++mi)
#pragma unroll
      for (int ni = 0; ni < 2; ++ni) {
        acc[mi][ni] = __builtin_amdgcn_mfma_f32_16x16x32_bf16(
            a0[mi][0], b0[ni][0], acc[mi][ni], 0, 0, 0);
        acc[mi][ni] = __builtin_amdgcn_mfma_f32_16x16x32_bf16(
            a0[mi][1], b0[ni][1], acc[mi][ni], 0, 0, 0);
      }
    __builtin_amdgcn_s_setprio(0);
    barf();

    // ---- P1: read A m4-7; stage B1(kt+1) -> nb ----
#pragma unroll
    for (int mi = 0; mi < 4; ++mi) { a4[mi][0] = RDA(b, 0, mi + 4); a4[mi][1] = RDA(b, 1, mi + 4); }
    if (h1) { ST_B(kt + 1, nb, 1); }
    barf();
    __builtin_amdgcn_s_setprio(1);
#pragma unroll
    for (int mi = 0; mi < 4; ++mi)
#pragma unroll
      for (int ni = 0; ni < 2; ++ni) {
        acc[4 + mi][ni] = __builtin_amdgcn_mfma_f32_16x16x32_bf16(
            a4[mi][0], b0[ni][0], acc[4 + mi][ni], 0, 0, 0);
        acc[4 + mi][ni] = __builtin_amdgcn_mfma_f32_16x16x32_bf16(
            a4[mi][1], b0[ni][1], acc[4 + mi][ni], 0, 0, 0);
      }
    __builtin_amdgcn_s_setprio(0);
    barf();

    // ---- P2: read B n2-3; stage A0(kt+2) -> b (A reads retired pre-P1-barrier) ----
#pragma unroll
    for (int ni = 0; ni < 2; ++ni) { b2[ni][0] = RDB(b, 0, ni + 2); b2[ni][1] = RDB(b, 1, ni + 2); }
    if (h2) { ST_A(kt + 2, b, 0); }
    barf();
    __builtin_amdgcn_s_setprio(1);
#pragma unroll
    for (int mi = 0; mi < 4; ++mi)
#pragma unroll
      for (int ni = 0; ni < 2; ++ni) {
        acc[4 + mi][2 + ni] = __builtin_amdgcn_mfma_f32_16x16x32_bf16(
            a4[mi][0], b2[ni][0], acc[4 + mi][2 + ni], 0, 0, 0);
        acc[4 + mi][2 + ni] = __builtin_amdgcn_mfma_f32_16x16x32_bf16(
            a4[mi][1], b2[ni][1], acc[4 + mi][2 + ni], 0, 0, 0);
      }
    __builtin_amdgcn_s_setprio(0);
    barf();

    // ---- P3: no reads; stage A1(kt+2) -> b ----
    if (h2) { ST_A(kt + 2, b, 1); }
    barf();
    __builtin_amdgcn_s_setprio(1);
#pragma unroll
    for (int mi = 0; mi < 4; ++mi)
#pragma unroll
      for (int ni = 0; ni < 2; ++ni) {
        acc[mi][2 + ni] = __builtin_amdgcn_mfma_f32_16x16x32_bf16(
            a0[mi][0], b2[ni][0], acc[mi][2 + ni], 0, 0, 0);
        acc[mi][2 + ni] = __builtin_amdgcn_mfma_f32_16x16x32_bf16(
            a0[mi][1], b2[ni][1], acc[mi][2 + ni], 0, 0, 0);
      }
    __builtin_amdgcn_s_setprio(0);
    barf();
  }
#undef ST_A
#undef ST_B
#undef RDA
#undef RDB
  __builtin_amdgcn_sched_barrier(0);

  const long crow0 = (long)bm * 256 + wr * 128;
  const long ccol0 = (long)bn * 256 + wc * 64;
  u16* C = (u16*)Cv + (long)bb * cBatch;
#pragma unroll
  for (int mi = 0; mi < 8; ++mi)
#pragma unroll
    for (int j = 0; j < 4; ++j) {
      long row = crow0 + mi * 16 + (l >> 4) * 4 + j;
      float rb = (BIAS == 1) ? bias[row] : 0.f;
#pragma unroll
      for (int ni = 0; ni < 4; ++ni) {
        long col = ccol0 + ni * 16 + (l & 15);
        C[row * ldc + col] = f2bf(acc[mi][ni][j] + rb);
      }
    }

  if (SUMS) {
    float* srep = sums + (blockIdx.x & 7) * 1536;
#pragma unroll
    for (int ni = 0; ni < 4; ++ni) {
      float s = 0.f, q = 0.f;
#pragma unroll
      for (int mi = 0; mi < 8; ++mi)
#pragma unroll
        for (int j = 0; j < 4; ++j) {
          float v = acc[mi][ni][j];
          s += v;
          q += v * v;
        }
      s += __shfl_xor(s, 16);
      q += __shfl_xor(q, 16);
      s += __shfl_xor(s, 32);
      q += __shfl_xor(q, 32);
      if (l < 16) {
        long col = ccol0 + ni * 16 + l;
        atomicAdd(&srep[col], s);
        atomicAdd(&srep[768 + col], q);
      }
    }
  }
}

// -------- generic NT GEMM (128x128, 4 waves): r5-exact --------
template <int BIAS, int OUT_ATOMIC, int SUMS>
__global__ __launch_bounds__(256) void gemm_nt(
    const u16* __restrict__ A, const u16* __restrict__ B, void* __restrict__ Cv,
    const float* __restrict__ bias, float* __restrict__ sums,
    int ntiles, long lda, long ldb, long ldc, int K,
    long aBatch, long bBatch, long cBatch) {
  __shared__ u16 As[2][128 * 32];
  __shared__ u16 Bs[2][128 * 32];

  const int bm = blockIdx.x / ntiles;
  const int bn = blockIdx.x % ntiles;
  const int bb = blockIdx.y;
  const int kChunk = K / gridDim.z;
  const long k0base = (long)blockIdx.z * kChunk;
  const int nt = kChunk >> 5;

  const u16* Ab = A + (long)bb * aBatch + (long)bm * 128 * lda + k0base;
  const u16* Bb = B + (long)bb * bBatch + (long)bn * 128 * ldb + k0base;

  const int t = threadIdx.x;
  const int w = t >> 6;
  const int l = t & 63;
  const int wr = w >> 1, wc = w & 1;

  const int cg = src_chunk(l);
  const long aoff = (long)(32 * w + (l >> 2)) * lda + cg;
  const long boff = (long)(32 * w + (l >> 2)) * ldb + cg;

  f32x4 acc[4][4] = {};

  gl16(Ab + aoff, &As[0][(32 * w) * 32]);
  gl16(Ab + aoff + 16 * lda, &As[0][(32 * w + 16) * 32]);
  gl16(Bb + boff, &Bs[0][(32 * w) * 32]);
  gl16(Bb + boff + 16 * ldb, &Bs[0][(32 * w + 16) * 32]);
  if (nt > 1) {
    gl16(Ab + aoff + 32, &As[1][(32 * w) * 32]);
    gl16(Ab + aoff + 16 * lda + 32, &As[1][(32 * w + 16) * 32]);
    gl16(Bb + boff + 32, &Bs[1][(32 * w) * 32]);
    gl16(Bb + boff + 16 * ldb + 32, &Bs[1][(32 * w + 16) * 32]);
  }

  const int koff = rd_koff(l);

  for (int tt = 0; tt < nt; ++tt) {
    const int cur = tt & 1;
    if (tt + 1 < nt)
      asm volatile("s_waitcnt vmcnt(4)" ::: "memory");
    else
      asm volatile("s_waitcnt vmcnt(0)" ::: "memory");
    __builtin_amdgcn_s_barrier();

    bf16x8 af[4], bfr[4];
#pragma unroll
    for (int mi = 0; mi < 4; ++mi)
      af[mi] = __builtin_bit_cast(
          bf16x8, *(const s16x8*)(&As[cur][(wr * 64 + mi * 16 + (l & 15)) * 32 + koff]));
#pragma unroll
    for (int ni = 0; ni < 4; ++ni)
      bfr[ni] = __builtin_bit_cast(
          bf16x8, *(const s16x8*)(&Bs[cur][(wc * 64 + ni * 16 + (l & 15)) * 32 + koff]));
#pragma unroll
    for (int mi = 0; mi < 4; ++mi)
#pragma unroll
      for (int ni = 0; ni < 4; ++ni)
        acc[mi][ni] = __builtin_amdgcn_mfma_f32_16x16x32_bf16(
            af[mi], bfr[ni], acc[mi][ni], 0, 0, 0);

    __builtin_amdgcn_s_barrier();
    if (tt + 2 < nt) {
      const long ko2 = (long)(tt + 2) * 32;
      gl16(Ab + aoff + ko2, &As[cur][(32 * w) * 32]);
      gl16(Ab + aoff + 16 * lda + ko2, &As[cur][(32 * w + 16) * 32]);
      gl16(Bb + boff + ko2, &Bs[cur][(32 * w) * 32]);
      gl16(Bb + boff + 16 * ldb + ko2, &Bs[cur][(32 * w + 16) * 32]);
    }
  }
  __builtin_amdgcn_sched_barrier(0);

  const long crow0 = (long)bm * 128 + wr * 64;
  const long ccol0 = (long)bn * 128 + wc * 64;

  if (OUT_ATOMIC) {
    float* C = (float*)Cv + (long)bb * cBatch;
#pragma unroll
    for (int mi = 0; mi < 4; ++mi)
#pragma unroll
      for (int j = 0; j < 4; ++j) {
        long row = crow0 + mi * 16 + (l >> 4) * 4 + j;
#pragma unroll
        for (int ni = 0; ni < 4; ++ni) {
          long col = ccol0 + ni * 16 + (l & 15);
          atomicAdd(&C[row * ldc + col], acc[mi][ni][j]);
        }
      }
  } else {
    u16* C = (u16*)Cv + (long)bb * cBatch;
#pragma unroll
    for (int mi = 0; mi < 4; ++mi)
#pragma unroll
      for (int j = 0; j < 4; ++j) {
        long row = crow0 + mi * 16 + (l >> 4) * 4 + j;
        float rb = (BIAS == 1) ? bias[row] : 0.f;
#pragma unroll
        for (int ni = 0; ni < 4; ++ni) {
          long col = ccol0 + ni * 16 + (l & 15);
          float cb = (BIAS == 2) ? bias[col] : 0.f;
          C[row * ldc + col] = f2bf(acc[mi][ni][j] + rb + cb);
        }
      }
  }

  if (SUMS && !OUT_ATOMIC) {
    float* srep = sums + (blockIdx.x & 7) * 1536;
#pragma unroll
    for (int ni = 0; ni < 4; ++ni) {
      float s = 0.f, q = 0.f;
#pragma unroll
      for (int mi = 0; mi < 4; ++mi)
#pragma unroll
        for (int j = 0; j < 4; ++j) {
          float v = acc[mi][ni][j];
          s += v;
          q += v * v;
        }
      s += __shfl_xor(s, 16);
      q += __shfl_xor(q, 16);
      s += __shfl_xor(s, 32);
      q += __shfl_xor(q, 32);
      if (l < 16) {
        long col = ccol0 + ni * 16 + l;
        atomicAdd(&srep[col], s);
        atomicAdd(&srep[768 + col], q);
      }
    }
  }
}

// ---------------- BN ----------------
__global__ void bn_stats(const float* __restrict__ sums, const float* __restrict__ gamma,
                         const float* __restrict__ beta, float* __restrict__ stats,
                         float invN) {
  int c = threadIdx.x;
  float s = 0.f, q = 0.f;
#pragma unroll
  for (int r = 0; r < 8; ++r) {
    s += sums[r * 1536 + c];
    q += sums[r * 1536 + 768 + c];
  }
  float mu = s * invN;
  float var = q * invN - mu * mu;
  float sc = gamma[c] * rsqrtf(var + 1e-5f);
  stats[c] = sc;
  stats[768 + c] = beta[c] - mu * sc;
}

template <int OUT_F32>
__global__ void bn_apply(const u16* __restrict__ pre, const u16* __restrict__ resid,
                         const float* __restrict__ stats, void* __restrict__ out,
                         long n8) {
  long stride = (long)gridDim.x * blockDim.x;
  for (long i = (long)blockIdx.x * blockDim.x + threadIdx.x; i < n8; i += stride) {
    long base = i * 8;
    int c = (int)(base % 768);
    f32x4 sc0 = *(const f32x4*)(stats + c);
    f32x4 sc1 = *(const f32x4*)(stats + c + 4);
    f32x4 sh0 = *(const f32x4*)(stats + 768 + c);
    f32x4 sh1 = *(const f32x4*)(stats + 768 + c + 4);
    s16x8 p = *(const s16x8*)(pre + base);
    s16x8 rv = *(const s16x8*)(resid + base);
    float o[8];
#pragma unroll
    for (int j = 0; j < 4; ++j)
      o[j] = bf2f((u16)p[j]) * sc0[j] + sh0[j] + bf2f((u16)rv[j]);
#pragma unroll
    for (int j = 0; j < 4; ++j)
      o[4 + j] = bf2f((u16)p[4 + j]) * sc1[j] + sh1[j] + bf2f((u16)rv[4 + j]);
    if (OUT_F32) {
      f32x4 o0, o1;
#pragma unroll
      for (int j = 0; j < 4; ++j) { o0[j] = o[j]; o1[j] = o[4 + j]; }
      f32x4* op = (f32x4*)((float*)out + base);
      op[0] = o0;
      op[1] = o1;
    } else {
      s16x8 ov;
#pragma unroll
      for (int j = 0; j < 8; ++j) ov[j] = (short)f2bf(o[j]);
      *(s16x8*)((u16*)out + base) = ov;
    }
  }
}

extern "C" void kernel_launch(void* const* d_in, const int* in_sizes, int n_in,
                              void* d_out, int out_size, void* d_ws, size_t ws_size,
                              hipStream_t stream) {
  const float* x = (const float*)d_in[0];
  const float* x0 = (const float*)d_in[1];
  const float* c_wg = (const float*)d_in[2];
  const float* c_bg = (const float*)d_in[3];
  const float* c_wt = (const float*)d_in[4];
  const float* c_bt = (const float*)d_in[5];
  const float* c_wp = (const float*)d_in[6];
  const float* c_bp = (const float*)d_in[7];
  const float* c_ww = (const float*)d_in[8];
  const float* c_gamma = (const float*)d_in[10];
  const float* c_beta = (const float*)d_in[11];
  const float* p_wg = (const float*)d_in[12];
  const float* p_bg = (const float*)d_in[13];
  const float* p_wt = (const float*)d_in[14];
  const float* p_bt = (const float*)d_in[15];
  const float* p_wp = (const float*)d_in[16];
  const float* p_bp = (const float*)d_in[17];
  const float* p_ww = (const float*)d_in[18];
  const float* p_gamma = (const float*)d_in[20];
  const float* p_beta = (const float*)d_in[21];

  char* ws = (char*)d_ws;
  const long NT = 32768;
  u16* xbf = (u16*)(ws + 0);
  u16* x0bf = (u16*)(ws + 50331648);
  u16* th = (u16*)(ws + 50331648);
  float* kvf_c = (float*)(ws + 75497472);
  float* kvf_p = (float*)(ws + 80216064);
  u16* kvb = (u16*)(ws + 82313216);
  u16* kvwT = (u16*)(ws + 84672512);
  u16* gphT = (u16*)(ws + 100663296);
  u16* wcat = (u16*)(ws + 184549376);
  u16* wt_c = (u16*)(ws + 186515456);
  u16* wt_p = (u16*)(ws + 187105280);
  u16* ww_c = (u16*)(ws + 187498496);
  u16* ww_p = (u16*)(ws + 188088320);
  float* biasb = (float*)(ws + 188481536);
  float* sums = (float*)(ws + 188489216);   // 2 x 8 x 1536 floats
  float* stats = (float*)(ws + 188587520);  // 1536 floats
  u16* zbf = xbf;
  u16* pre = gphT;

  // ---- prep ----
  cvt_in2<<<4096, 256, 0, stream>>>(x, x0, xbf, x0bf, NT * 768 / 8);
  prep_w<<<480, 256, 0, stream>>>(c_wg, c_wp, p_wg, p_wp, c_wt, p_wt, c_ww, p_ww,
                                  wcat, wt_c, wt_p, ww_c, ww_p);
  prep_b<<<104, 256, 0, stream>>>(c_bg, c_bp, p_bg, p_bp, c_bt, p_bt, biasb, sums);

  // ---- fused gphT[1280][32768] = Wcat @ x0^T (+row bias) ----
  gemm_nt_big<1, 0><<<dim3(5 * 128, 1, 1), 512, 0, stream>>>(
      wcat, x0bf, gphT, biasb, nullptr, 128, 768, 768, 32768, 768, 0, 0, 0);
  hipMemsetAsync(kvf_c, 0, 4718592 + 2097152, stream);

  // ================= CNL (D=384) =================
  gemm_nt<2, 0, 0><<<dim3(256 * 3, 1, 1), 256, 0, stream>>>(
      xbf, wt_c, th, biasb + 1280, nullptr, 3, 768, 768, 384, 768, 0, 0, 0);
  gemm_nt<0, 1, 0><<<dim3(9, 8, 4), 256, 0, stream>>>(
      gphT + (long)384 * 32768, gphT, kvf_c, nullptr, nullptr, 3, 32768, 32768,
      384, 4096, 4096, 4096, (long)384 * 384);
  cvt_flat8<<<576, 256, 0, stream>>>(kvf_c, kvb, (long)8 * 384 * 384 / 8, 1.f / 4096.f);
  gemm_nt<0, 0, 0><<<dim3(18, 8, 1), 256, 0, stream>>>(
      ww_c, kvb, kvwT, nullptr, nullptr, 3, 384, 384, 384, 384, 0,
      (long)384 * 384, (long)768 * 384);
  gemm_nt_big<0, 1><<<dim3(48, 8, 1), 512, 0, stream>>>(
      th, kvwT, pre, nullptr, sums, 3, 384, 384, 768, 384, (long)4096 * 384,
      (long)768 * 384, (long)4096 * 768);
  bn_stats<<<1, 768, 0, stream>>>(sums, c_gamma, c_beta, stats, 1.f / 32768.f);
  bn_apply<0><<<2048, 256, 0, stream>>>(pre, xbf, stats, zbf, NT * 768 / 8);

  // ================= PNL (D=192, padded to 256; K trimmed to 192) =================
  gemm_nt<2, 0, 0><<<dim3(256 * 2, 1, 1), 256, 0, stream>>>(
      zbf, wt_p, th, biasb + 1664, nullptr, 2, 768, 768, 256, 768, 0, 0, 0);
  gemm_nt<0, 1, 0><<<dim3(4, 8, 8), 256, 0, stream>>>(
      gphT + (long)1024 * 32768, gphT + (long)768 * 32768, kvf_p, nullptr, nullptr,
      2, 32768, 32768, 256, 4096, 4096, 4096, (long)256 * 256);
  cvt_flat8<<<256, 256, 0, stream>>>(kvf_p, kvb, (long)8 * 256 * 256 / 8, 1.f / 4096.f);
  gemm_nt<0, 0, 0><<<dim3(12, 8, 1), 256, 0, stream>>>(
      ww_p, kvb, kvwT, nullptr, nullptr, 2, 256, 256, 256, 192, 0,
      (long)256 * 256, (long)768 * 256);
  gemm_nt_big<0, 1><<<dim3(48, 8, 1), 512, 0, stream>>>(
      th, kvwT, pre, nullptr, sums + 8 * 1536, 3, 256, 256, 768, 192,
      (long)4096 * 256, (long)768 * 256, (long)4096 * 768);
  bn_stats<<<1, 768, 0, stream>>>(sums + 8 * 1536, p_gamma, p_beta, stats, 1.f / 32768.f);
  bn_apply<1><<<2048, 256, 0, stream>>>(pre, zbf, stats, (float*)d_out, NT * 768 / 8);
}